// Round 2
// baseline (3132.506 us; speedup 1.0000x reference)
//
#include <hip/hip_runtime.h>
#include <math.h>

#define BB 32
#define NN 1024
#define KNNK 20
#define PTS (BB*NN)   // 32768

typedef __attribute__((ext_vector_type(8)))  short short8;
typedef __attribute__((ext_vector_type(4)))  float f32x4;
typedef __attribute__((ext_vector_type(16))) float f32x16;

__device__ __forceinline__ float lrelu(float v){ return v >= 0.f ? v : 0.2f*v; }

__device__ __forceinline__ unsigned short f2b(float x){
    union { float f; unsigned u; } c; c.f = x;
    unsigned r = c.u + 0x7FFFu + ((c.u >> 16) & 1u);
    return (unsigned short)(r >> 16);
}

// ---------------- squared norms per point ----------------
__global__ void sq_kernel(const float* __restrict__ x, int stride, int C, float* __restrict__ xx){
    int pn = blockIdx.x*256 + threadIdx.x;
    if (pn >= PTS) return;
    const float* r = x + (size_t)pn*stride;
    float s = 0.f;
    for (int c = 0; c < C; ++c){ float v = r[c]; s = fmaf(v, v, s); }
    xx[pn] = s;
}

// ---------------- FUSED knn: distance GEMM + radix-bisection top-20, no D matrix ----------------
// Block = 32 rows of one batch (4 waves x 8 rows). Lane l accumulates cols l+64q (q=0..15)
// -> acc[8][16] in VGPRs == the u[16]-per-lane layout bisection wants. Distances never hit memory.
// B streams via LDS k-chunks of 8, XOR-swizzled (slot ^= (col>>2)&1: conflict-free for the
// stride-32B column read). A-rows read from the same Bs tile (rows are a subset of cols).
// FMA k-order and epilogue expression identical to the old dist_kernel -> bit-identical
// distances -> identical neighbor sets.
template<int C>
__global__ void __launch_bounds__(256, 2) knn_kernel(const float* __restrict__ x, int stride,
                                                     const float* __restrict__ xx,
                                                     int* __restrict__ idxout){
    constexpr int KC = 8;
    __shared__ __align__(16) float Bs[NN*KC];   // 32 KB, swizzled [col][8]
    __shared__ float xs[NN];                    // 4 KB
    // XCD-chunked swizzle: 1024 blocks, each XCD gets 4 whole batches (B L2-resident).
    int bid = (int)blockIdx.x;
    bid = (bid & 7)*128 + (bid >> 3);
    const int b  = bid >> 5;
    const int rb = bid & 31;
    const int r0 = rb * 32;
    const int tid = threadIdx.x;
    const int wv = tid >> 6, lane = tid & 63;
    const float* xb = x + (size_t)b*NN*stride;

    // stage xx for this batch
    *(float4*)&xs[tid*4] = *(const float4*)&xx[b*NN + tid*4];

    float acc[8][16];
    #pragma unroll
    for (int r=0;r<8;++r)
        #pragma unroll
        for (int q=0;q<16;++q) acc[r][q] = 0.f;

    const int wrow = wv*8;          // wave's first local row
    const int swl  = (lane>>2)&1;   // B-read swizzle bit (independent of q)

    #pragma unroll 1
    for (int kc = 0; kc < C; kc += KC){
        __syncthreads();
        // stage B chunk: thread t -> (col = t>>1, half = t&1), 8 passes of float4
        #pragma unroll
        for (int ps = 0; ps < 8; ++ps){
            int i = tid + ps*256;             // 0..2047
            int col = i >> 1, half = i & 1;
            float4 v;
            if constexpr (C == 3){
                float vv[4];
                #pragma unroll
                for (int j = 0; j < 4; ++j){
                    int k = half*4 + j;
                    vv[j] = (k < 3) ? xb[(size_t)col*3 + k] : 0.f;
                }
                v = make_float4(vv[0], vv[1], vv[2], vv[3]);
            } else {
                v = *(const float4*)&xb[(size_t)col*stride + kc + half*4];
            }
            int sw = half ^ ((col>>2)&1);
            *(float4*)&Bs[col*KC + sw*4] = v;
        }
        __syncthreads();
        #pragma unroll
        for (int s = 0; s < 2; ++s){          // two 4-k sub-chunks
            float4 ar[8];
            #pragma unroll
            for (int r=0;r<8;++r){
                int arow = r0 + wrow + r;
                int swa = s ^ ((arow>>2)&1);
                ar[r] = *(const float4*)&Bs[arow*KC + swa*4];
            }
            int offb = (s ^ swl)*4;
            #pragma unroll
            for (int q=0;q<16;++q){
                float4 bv = *(const float4*)&Bs[(lane + 64*q)*KC + offb];
                #pragma unroll
                for (int r=0;r<8;++r){
                    acc[r][q] = fmaf(ar[r].x, bv.x, acc[r][q]);
                    acc[r][q] = fmaf(ar[r].y, bv.y, acc[r][q]);
                    acc[r][q] = fmaf(ar[r].z, bv.z, acc[r][q]);
                    acc[r][q] = fmaf(ar[r].w, bv.w, acc[r][q]);
                }
            }
        }
    }

    // ---- per-row epilogue: distance map + radix bisection + ballot emission ----
    const unsigned long long lt = (lane == 0) ? 0ull : ((~0ull) >> (64 - lane));
    #pragma unroll 1
    for (int r = 0; r < 8; ++r){
        const int lrow = r0 + wrow + r;
        const float xi = xs[lrow];
        unsigned u[16];
        #pragma unroll
        for (int q = 0; q < 16; ++q){
            float d = 2.f*acc[r][q] - xi - xs[lane + 64*q];
            unsigned bits = __float_as_uint(d);
            unsigned m = (bits & 0x80000000u) ? 0xFFFFFFFFu : 0x80000000u;
            u[q] = bits ^ m;
        }
        unsigned t = 0u;
        for (int bb = 31; bb >= 0; --bb){
            unsigned cand = t | (1u << bb);
            int cnt = 0;
            #pragma unroll
            for (int q = 0; q < 16; ++q)
                cnt += (int)__popcll(__ballot(u[q] >= cand));
            if (cnt >= KNNK) t = cand;
        }
        int* orow = idxout + ((size_t)b*NN + lrow) * KNNK;
        int cbase = 0;
        #pragma unroll
        for (int q = 0; q < 16; ++q){
            bool gt2 = (u[q] > t);
            unsigned long long mask = __ballot(gt2);
            if (gt2) orow[cbase + (int)__popcll(mask & lt)] = q*64 + lane;
            cbase += (int)__popcll(mask);
        }
        #pragma unroll
        for (int q = 0; q < 16; ++q){
            bool eq = (u[q] == t);
            unsigned long long mask = __ballot(eq);
            int pos = cbase + (int)__popcll(mask & lt);
            if (eq && pos < KNNK) orow[pos] = q*64 + lane;
            cbase += (int)__popcll(mask);
        }
    }
}

// ---------------- G GEMMs: G1 = X @ W[:, :C]^T ; Gd = X @ (W[:,C:]-W[:, :C])^T ----------------
template<int C, int O>
__global__ void __launch_bounds__(256) gemmG_kernel(const float* __restrict__ x, int stride,
                                                    const float* __restrict__ W,
                                                    float* __restrict__ G1, float* __restrict__ Gd){
    constexpr int KC = (C < 32 ? C : 32);
    __shared__ float Xl [KC][68];
    __shared__ float W1l[KC][68];
    __shared__ float W2l[KC][68];
    const int tid = threadIdx.x;
    const int r0 = blockIdx.x * 64;
    const int o0 = blockIdx.y * 64;
    const int rt = tid & 15, ct = tid >> 4;

    float a1[4][4] = {{0.f}}, a2[4][4] = {{0.f}};
    for (int kc = 0; kc < C; kc += KC){
        __syncthreads();
        for (int i = tid; i < KC*64; i += 256){
            int k = i % KC, rr = i / KC;
            Xl [k][rr] = x[(size_t)(r0+rr)*stride + kc + k];
            W1l[k][rr] = W[(size_t)(o0+rr)*(2*C) + kc + k];
            W2l[k][rr] = W[(size_t)(o0+rr)*(2*C) + C + kc + k];
        }
        __syncthreads();
        #pragma unroll
        for (int k = 0; k < KC; ++k){
            float4 xa = *(const float4*)&Xl [k][rt*4];
            float4 w1 = *(const float4*)&W1l[k][ct*4];
            float4 w2 = *(const float4*)&W2l[k][ct*4];
            float xv[4] = {xa.x, xa.y, xa.z, xa.w};
            #pragma unroll
            for (int i = 0; i < 4; ++i){
                a1[i][0] = fmaf(xv[i], w1.x, a1[i][0]);
                a1[i][1] = fmaf(xv[i], w1.y, a1[i][1]);
                a1[i][2] = fmaf(xv[i], w1.z, a1[i][2]);
                a1[i][3] = fmaf(xv[i], w1.w, a1[i][3]);
                a2[i][0] = fmaf(xv[i], w2.x, a2[i][0]);
                a2[i][1] = fmaf(xv[i], w2.y, a2[i][1]);
                a2[i][2] = fmaf(xv[i], w2.z, a2[i][2]);
                a2[i][3] = fmaf(xv[i], w2.w, a2[i][3]);
            }
        }
    }
    #pragma unroll
    for (int i = 0; i < 4; ++i){
        size_t row = (size_t)(r0 + rt*4 + i);
        float4 g1v = make_float4(a1[i][0], a1[i][1], a1[i][2], a1[i][3]);
        float4 gdv = make_float4(a2[i][0]-a1[i][0], a2[i][1]-a1[i][1],
                                 a2[i][2]-a1[i][2], a2[i][3]-a1[i][3]);
        *(float4*)&G1[row*O + o0 + ct*4] = g1v;
        *(float4*)&Gd[row*O + o0 + ct*4] = gdv;
    }
}

// ---------------- gather (float4): per (point, 4 cols) max/sum/sumsq over k ----------------
template<int O>
__global__ void __launch_bounds__(256) gather_kernel(const float* __restrict__ G1,
                                                     const float* __restrict__ Gd,
                                                     const int* __restrict__ idxg, int bgbase,
                                                     float* __restrict__ catslice,
                                                     float* __restrict__ stats){
    constexpr int OG = O/4;
    constexpr int PP = 256/OG;
    constexpr int NP = 16;
    __shared__ int nbs[NP][KNNK];
    const int nwg = (int)gridDim.x;
    int bid = (int)blockIdx.x;
    if ((nwg & 7) == 0){
        const int cpx = nwg >> 3;
        bid = (bid & 7) * cpx + (bid >> 3);
    }
    const int tid = threadIdx.x;
    const int p0 = bid * NP;
    for (int i = tid; i < NP*KNNK; i += 256){
        int pp = i / KNNK, kk = i - pp*KNNK;
        int pl = p0 + pp;
        nbs[pp][kk] = ((pl >> 10) << 10) + idxg[(size_t)(bgbase + pl)*KNNK + kk];
    }
    __syncthreads();
    const int o4 = (tid % OG)*4;
    const int pq = tid / OG;
    float S1[4] = {0.f,0.f,0.f,0.f}, S2[4] = {0.f,0.f,0.f,0.f};
    for (int pp = pq; pp < NP; pp += PP){
        int pl = p0 + pp;
        float4 dv = *(const float4*)&Gd[(size_t)pl*O + o4];
        float d[4] = {dv.x, dv.y, dv.z, dv.w};
        float mx[4] = {-INFINITY,-INFINITY,-INFINITY,-INFINITY};
        float ls[4] = {0.f,0.f,0.f,0.f}, lq[4] = {0.f,0.f,0.f,0.f};
        #pragma unroll
        for (int kk = 0; kk < KNNK; ++kk){
            float4 gv = *(const float4*)&G1[(size_t)nbs[pp][kk]*O + o4];
            float ga[4] = {gv.x, gv.y, gv.z, gv.w};
            #pragma unroll
            for (int c = 0; c < 4; ++c){
                mx[c] = fmaxf(mx[c], ga[c]);
                ls[c] += ga[c];
                lq[c] = fmaf(ga[c], ga[c], lq[c]);
            }
        }
        float4 outv;
        float* op = &outv.x;
        #pragma unroll
        for (int c = 0; c < 4; ++c){
            S1[c] += ls[c] + 20.f*d[c];
            S2[c] += lq[c] + 2.f*d[c]*ls[c] + 20.f*d[c]*d[c];
            op[c] = mx[c] + d[c];
        }
        *(float4*)&catslice[(size_t)(bgbase + pl)*512 + o4] = outv;
    }
    int rep = bid & 63;
    #pragma unroll
    for (int c = 0; c < 4; ++c){
        atomicAdd(&stats[rep*2*O + o4 + c],     S1[c]);
        atomicAdd(&stats[rep*2*O + O + o4 + c], S2[c]);
    }
}

// ---------------- finalize BN stats ----------------
__global__ void fin_kernel(const float* __restrict__ stats, int O, float cnt,
                           float* __restrict__ mean, float* __restrict__ invstd){
    int o = threadIdx.x;
    if (o >= O) return;
    float s1 = 0.f, s2 = 0.f;
    for (int r = 0; r < 64; ++r){
        s1 += stats[r*2*O + o];
        s2 += stats[r*2*O + O + o];
    }
    float m = s1 / cnt;
    float v = s2 / cnt - m*m;
    mean[o] = m;
    invstd[o] = rsqrtf(v + 1e-5f);
}

// ---------------- apply BN+LReLU in place on cat slice ----------------
template<int O>
__global__ void apply_kernel(float* __restrict__ catslice,
                             const float* __restrict__ mean, const float* __restrict__ invstd,
                             const float* __restrict__ g, const float* __restrict__ bt){
    int i = blockIdx.x*256 + threadIdx.x;
    int pn = i / O, o = i - pn*O;
    float* p = &catslice[(size_t)pn*512 + o];
    float hn = (*p - mean[o]) * invstd[o] * g[o] + bt[o];
    *p = lrelu(hn);
}

// ---------------- fp32 -> bf16 conversion (4 elems/thread) ----------------
__global__ void tob16_kernel(const float* __restrict__ src, unsigned short* __restrict__ dst, int n4){
    int i = blockIdx.x*256 + threadIdx.x;
    if (i >= n4) return;
    float4 v = *(const float4*)&src[(size_t)i*4];
    ushort4 o;
    o.x = f2b(v.x); o.y = f2b(v.y); o.z = f2b(v.z); o.w = f2b(v.w);
    *(ushort4*)&dst[(size_t)i*4] = o;
}

// ---------------- layer 5 MFMA: 32x32x16 frags, 64x64/wave, 128x128/block ----------------
__global__ void __launch_bounds__(256) l5m_kernel(const unsigned short* __restrict__ Am,
                                                  const unsigned short* __restrict__ Bm,
                                                  float* __restrict__ pmax,
                                                  float* __restrict__ psum,
                                                  float* __restrict__ psq){
    __shared__ __align__(16) unsigned short As[128][64];
    __shared__ __align__(16) unsigned short Bs[128][64];
    const int tid = threadIdx.x;
    const int r0 = blockIdx.x * 128;
    const int o0 = blockIdx.y * 128;
    const int w = tid >> 6, lane = tid & 63;
    const int m32 = lane & 31, kh = lane >> 5;
    const int wm = (w & 1) * 64;
    const int wn = (w >> 1) * 64;

    f32x16 acc[2][2];
    #pragma unroll
    for (int i=0;i<2;++i)
        #pragma unroll
        for (int j=0;j<2;++j)
            #pragma unroll
            for (int r=0;r<16;++r) acc[i][j][r] = 0.f;

    for (int kc = 0; kc < 512; kc += 64){
        __syncthreads();
        #pragma unroll
        for (int t = 0; t < 4; ++t){
            int i = tid + t*256;
            int rr = i >> 3, ch = i & 7;
            int sl = ch ^ (rr & 7);
            *(uint4*)&As[rr][sl*8] = *(const uint4*)&Am[(size_t)(r0+rr)*512 + kc + ch*8];
            *(uint4*)&Bs[rr][sl*8] = *(const uint4*)&Bm[(size_t)(o0+rr)*512 + kc + ch*8];
        }
        __syncthreads();
        #pragma unroll
        for (int q = 0; q < 4; ++q){
            int lk = q*2 + kh;
            short8 a[2], bfr[2];
            #pragma unroll
            for (int mb = 0; mb < 2; ++mb){
                int rA = wm + mb*32 + m32;
                a[mb] = *(const short8*)&As[rA][(lk ^ (rA & 7))*8];
            }
            #pragma unroll
            for (int nb = 0; nb < 2; ++nb){
                int rB = wn + nb*32 + m32;
                bfr[nb] = *(const short8*)&Bs[rB][(lk ^ (rB & 7))*8];
            }
            #pragma unroll
            for (int mb = 0; mb < 2; ++mb)
                #pragma unroll
                for (int nb = 0; nb < 2; ++nb)
                    acc[mb][nb] = __builtin_amdgcn_mfma_f32_32x32x16_bf16(a[mb], bfr[nb], acc[mb][nb], 0, 0, 0);
        }
    }
    __syncthreads();
    float* red = (float*)&As[0][0];
    #pragma unroll
    for (int nb = 0; nb < 2; ++nb){
        float mx = -INFINITY, s1 = 0.f, s2 = 0.f;
        #pragma unroll
        for (int mb = 0; mb < 2; ++mb)
            #pragma unroll
            for (int r = 0; r < 16; ++r){
                float v = acc[mb][nb][r];
                mx = fmaxf(mx, v); s1 += v; s2 = fmaf(v, v, s2);
            }
        mx = fmaxf(mx, __shfl_xor(mx, 32));
        s1 += __shfl_xor(s1, 32);
        s2 += __shfl_xor(s2, 32);
        if (lane < 32){
            int col = wn + nb*32 + m32;
            float* p = red + ((size_t)(w & 1) * 128 + col) * 3;
            p[0] = mx; p[1] = s1; p[2] = s2;
        }
    }
    __syncthreads();
    if (tid < 128){
        const float* p0 = red + (size_t)tid*3;
        const float* p1 = red + (size_t)(128 + tid)*3;
        float mx = fmaxf(p0[0], p1[0]);
        float s1 = p0[1] + p1[1];
        float s2 = p0[2] + p1[2];
        size_t pi = (size_t)blockIdx.x*1024 + o0 + tid;
        pmax[pi] = mx; psum[pi] = s1; psq[pi] = s2;
    }
}

__global__ void fin5_kernel(const float* __restrict__ pmax, const float* __restrict__ psum,
                            const float* __restrict__ psq,
                            const float* __restrict__ g, const float* __restrict__ bt,
                            float* __restrict__ out){
    int o = blockIdx.x*256 + threadIdx.x; // 1024 total
    float s1 = 0.f, s2 = 0.f;
    for (int r = 0; r < 256; ++r){
        s1 += psum[(size_t)r*1024 + o];
        s2 += psq [(size_t)r*1024 + o];
    }
    float m  = s1 / 32768.f;
    float v  = s2 / 32768.f - m*m;
    float is = rsqrtf(v + 1e-5f);
    float gg = g[o], bb2 = bt[o];
    for (int b = 0; b < 32; ++b){
        float mx = -INFINITY;
        #pragma unroll
        for (int ns = 0; ns < 8; ++ns) mx = fmaxf(mx, pmax[((size_t)b*8 + ns)*1024 + o]);
        float hn = (mx - m) * is * gg + bb2;
        out[(size_t)b*1024 + o] = lrelu(hn);
    }
}

extern "C" void kernel_launch(void* const* d_in, const int* in_sizes, int n_in,
                              void* d_out, int out_size, void* d_ws, size_t ws_size,
                              hipStream_t stream) {
    (void)in_sizes; (void)n_in; (void)out_size;
    const float* x  = (const float*)d_in[0];
    const float* W1 = (const float*)d_in[1];  const float* g1 = (const float*)d_in[2];  const float* b1 = (const float*)d_in[3];
    const float* W2 = (const float*)d_in[4];  const float* g2 = (const float*)d_in[5];  const float* b2 = (const float*)d_in[6];
    const float* W3 = (const float*)d_in[7];  const float* g3 = (const float*)d_in[8];  const float* b3 = (const float*)d_in[9];
    const float* W4 = (const float*)d_in[10]; const float* g4 = (const float*)d_in[11]; const float* b4 = (const float*)d_in[12];
    const float* W5 = (const float*)d_in[13]; const float* g5 = (const float*)d_in[14]; const float* b5 = (const float*)d_in[15];
    float* out = (float*)d_out;

    const size_t fixedBytes = (size_t)PTS*512*4 + (size_t)PTS*KNNK*4 + (size_t)PTS*4
                            + (size_t)64*2*256*4 + 2048*4 + 3*(size_t)256*1024*4
                            + (size_t)1024*512*2;
    int CB;
    if      (ws_size >= fixedBytes + (size_t)32*NN*NN*4) CB = 32;
    else if (ws_size >= fixedBytes + (size_t)16*NN*NN*4) CB = 16;
    else                                                 CB = 8;
    const size_t Rbytes = (size_t)CB*NN*NN*4;

    char* wsp = (char*)d_ws;
    float* cat    = (float*)wsp; wsp += (size_t)PTS*512*4;
    char*  R      = wsp;         wsp += Rbytes;
    int*   idx    = (int*)  wsp; wsp += (size_t)PTS*KNNK*4;
    float* xx     = (float*)wsp; wsp += (size_t)PTS*4;
    float* stats  = (float*)wsp; wsp += (size_t)64*2*256*4;
    float* mean   = (float*)wsp; wsp += 1024*4;
    float* invstd = (float*)wsp; wsp += 1024*4;
    float* pmax   = (float*)wsp; wsp += (size_t)256*1024*4;
    float* psum   = (float*)wsp; wsp += (size_t)256*1024*4;
    float* psq    = (float*)wsp; wsp += (size_t)256*1024*4;
    unsigned short* W5b = (unsigned short*)wsp; wsp += (size_t)1024*512*2;

    float* G1    = (float*)R;
    float* GdS   = (float*)(R + (size_t)16*1024*1024);
    float* GdB   = (float*)(R + (size_t)32*1024*1024);
    unsigned short* catB = (unsigned short*)R;

    const float cntE = (float)(PTS*KNNK);
    const bool bigG = (Rbytes >= (size_t)64*1024*1024);

    // ---- Layer 1: C=3 -> O=64 ----
    sq_kernel<<<PTS/256, 256, 0, stream>>>(x, 3, 3, xx);
    knn_kernel<3><<<1024, 256, 0, stream>>>(x, 3, xx, idx);
    hipMemsetAsync(stats, 0, 64*2*256*4, stream);
    gemmG_kernel<3,64><<<dim3(512,1), 256, 0, stream>>>(x, 3, W1, G1, GdS);
    gather_kernel<64><<<2048, 256, 0, stream>>>(G1, GdS, idx, 0, cat + 0, stats);
    fin_kernel<<<1, 64, 0, stream>>>(stats, 64, cntE, mean, invstd);
    apply_kernel<64><<<PTS*64/256, 256, 0, stream>>>(cat + 0, mean, invstd, g1, b1);

    // ---- Layer 2: C=64 -> O=64 ----
    sq_kernel<<<PTS/256, 256, 0, stream>>>(cat + 0, 512, 64, xx);
    knn_kernel<64><<<1024, 256, 0, stream>>>(cat + 0, 512, xx, idx);
    hipMemsetAsync(stats, 0, 64*2*256*4, stream);
    gemmG_kernel<64,64><<<dim3(512,1), 256, 0, stream>>>(cat + 0, 512, W2, G1, GdS);
    gather_kernel<64><<<2048, 256, 0, stream>>>(G1, GdS, idx, 0, cat + 64, stats);
    fin_kernel<<<1, 64, 0, stream>>>(stats, 64, cntE, mean, invstd);
    apply_kernel<64><<<PTS*64/256, 256, 0, stream>>>(cat + 64, mean, invstd, g2, b2);

    // ---- Layer 3: C=64 -> O=128 ----
    sq_kernel<<<PTS/256, 256, 0, stream>>>(cat + 64, 512, 64, xx);
    knn_kernel<64><<<1024, 256, 0, stream>>>(cat + 64, 512, xx, idx);
    hipMemsetAsync(stats, 0, 64*2*256*4, stream);
    gemmG_kernel<64,128><<<dim3(512,2), 256, 0, stream>>>(cat + 64, 512, W3, G1, GdS);
    gather_kernel<128><<<2048, 256, 0, stream>>>(G1, GdS, idx, 0, cat + 128, stats);
    fin_kernel<<<1, 128, 0, stream>>>(stats, 128, cntE, mean, invstd);
    apply_kernel<128><<<PTS*128/256, 256, 0, stream>>>(cat + 128, mean, invstd, g3, b3);

    // ---- Layer 4: C=128 -> O=256 ----
    sq_kernel<<<PTS/256, 256, 0, stream>>>(cat + 128, 512, 128, xx);
    knn_kernel<128><<<1024, 256, 0, stream>>>(cat + 128, 512, xx, idx);
    hipMemsetAsync(stats, 0, 64*2*256*4, stream);
    if (bigG){
        gemmG_kernel<128,256><<<dim3(512,4), 256, 0, stream>>>(cat + 128, 512, W4, G1, GdB);
        gather_kernel<256><<<2048, 256, 0, stream>>>(G1, GdB, idx, 0, cat + 256, stats);
    } else {
        for (int bg = 0; bg < 4; ++bg){
            gemmG_kernel<128,256><<<dim3(128,4), 256, 0, stream>>>(cat + 128 + (size_t)bg*8192*512, 512, W4, G1, GdS);
            gather_kernel<256><<<512, 256, 0, stream>>>(G1, GdS, idx, bg*8192, cat + 256, stats);
        }
    }
    fin_kernel<<<1, 256, 0, stream>>>(stats, 256, cntE, mean, invstd);
    apply_kernel<256><<<PTS*256/256, 256, 0, stream>>>(cat + 256, mean, invstd, g4, b4);

    // ---- Layer 5: bf16 MFMA GEMM with fused max/stats ----
    tob16_kernel<<<PTS*512/4/256, 256, 0, stream>>>(cat, catB, PTS*512/4);
    tob16_kernel<<<1024*512/4/256, 256, 0, stream>>>(W5, W5b, 1024*512/4);
    l5m_kernel<<<dim3(256, 8), 256, 0, stream>>>(catB, W5b, pmax, psum, psq);
    fin5_kernel<<<4, 256, 0, stream>>>(pmax, psum, psq, g5, b5, out);
}

// Round 3
// 1369.762 us; speedup vs baseline: 2.2869x; 2.2869x over previous
//
#include <hip/hip_runtime.h>
#include <math.h>

#define BB 32
#define NN 1024
#define KNNK 20
#define PTS (BB*NN)   // 32768

typedef __attribute__((ext_vector_type(8)))  short short8;
typedef __attribute__((ext_vector_type(4)))  float f32x4;
typedef __attribute__((ext_vector_type(16))) float f32x16;

__device__ __forceinline__ float lrelu(float v){ return v >= 0.f ? v : 0.2f*v; }

__device__ __forceinline__ unsigned short f2b(float x){
    union { float f; unsigned u; } c; c.f = x;
    unsigned r = c.u + 0x7FFFu + ((c.u >> 16) & 1u);
    return (unsigned short)(r >> 16);
}

// ---------------- squared norms per point ----------------
__global__ void sq_kernel(const float* __restrict__ x, int stride, int C, float* __restrict__ xx){
    int pn = blockIdx.x*256 + threadIdx.x;
    if (pn >= PTS) return;
    const float* r = x + (size_t)pn*stride;
    float s = 0.f;
    for (int c = 0; c < C; ++c){ float v = r[c]; s = fmaf(v, v, s); }
    xx[pn] = s;
}

// ---------------- FUSED knn: distance GEMM + radix-bisection top-20, no D matrix ----------------
// 512 threads = 8 waves x 4 rows -> 32 rows/block, 1024 blocks. acc[4][16] = 64 VGPRs.
// EPILOGUE IS FULLY UNROLLED: round-2 regression was `#pragma unroll 1` over r with
// acc[r][q] runtime-indexed -> whole acc to scratch (4.9 GB spill writes, rule #20).
// Lane l holds cols l+64q (q=0..15) == the u[16] layout bisection wants.
// B streams via LDS k-chunks of 8, XOR-swizzled; A-rows broadcast-read from same tile.
// FMA k-order + epilogue expression identical -> bit-identical distances.
template<int C>
__global__ void __launch_bounds__(512, 4) knn_kernel(const float* __restrict__ x, int stride,
                                                     const float* __restrict__ xx,
                                                     int* __restrict__ idxout){
    constexpr int KC = 8;
    __shared__ __align__(16) float Bs[NN*KC];   // 32 KB, swizzled [col][8]
    __shared__ float xs[NN];                    // 4 KB
    // XCD-chunked swizzle: each XCD gets 4 whole batches (B slice L2-resident).
    int bid = (int)blockIdx.x;
    bid = (bid & 7)*128 + (bid >> 3);
    const int b  = bid >> 5;
    const int rb = bid & 31;
    const int r0 = rb * 32;
    const int tid = threadIdx.x;
    const int wv = tid >> 6, lane = tid & 63;
    const float* xb = x + (size_t)b*NN*stride;

    if (tid < 256) *(float4*)&xs[tid*4] = *(const float4*)&xx[b*NN + tid*4];

    float acc[4][16];
    #pragma unroll
    for (int r=0;r<4;++r)
        #pragma unroll
        for (int q=0;q<16;++q) acc[r][q] = 0.f;

    const int wrow = wv*4;          // wave's first local row
    const int swl  = (lane>>2)&1;   // B-read swizzle bit

    #pragma unroll 1
    for (int kc = 0; kc < C; kc += KC){
        __syncthreads();
        // stage B chunk: i -> (col = i>>1, half = i&1), 4 passes of float4 (512 thr)
        #pragma unroll
        for (int ps = 0; ps < 4; ++ps){
            int i = tid + ps*512;             // 0..2047
            int col = i >> 1, half = i & 1;
            float4 v;
            if constexpr (C == 3){
                float vv[4];
                #pragma unroll
                for (int j = 0; j < 4; ++j){
                    int k = half*4 + j;
                    vv[j] = (k < 3) ? xb[(size_t)col*3 + k] : 0.f;
                }
                v = make_float4(vv[0], vv[1], vv[2], vv[3]);
            } else {
                v = *(const float4*)&xb[(size_t)col*stride + kc + half*4];
            }
            int sw = half ^ ((col>>2)&1);
            *(float4*)&Bs[col*KC + sw*4] = v;
        }
        __syncthreads();
        #pragma unroll
        for (int s = 0; s < 2; ++s){          // two 4-k sub-chunks
            float4 ar[4];
            #pragma unroll
            for (int r=0;r<4;++r){
                int arow = r0 + wrow + r;
                int swa = s ^ ((arow>>2)&1);
                ar[r] = *(const float4*)&Bs[arow*KC + swa*4];
            }
            int offb = (s ^ swl)*4;
            #pragma unroll
            for (int q=0;q<16;++q){
                float4 bv = *(const float4*)&Bs[(lane + 64*q)*KC + offb];
                #pragma unroll
                for (int r=0;r<4;++r){
                    acc[r][q] = fmaf(ar[r].x, bv.x, acc[r][q]);
                    acc[r][q] = fmaf(ar[r].y, bv.y, acc[r][q]);
                    acc[r][q] = fmaf(ar[r].z, bv.z, acc[r][q]);
                    acc[r][q] = fmaf(ar[r].w, bv.w, acc[r][q]);
                }
            }
        }
    }

    // ---- per-row epilogue: distance map + radix bisection + ballot emission ----
    // FULLY UNROLLED over r: all acc/u indices compile-time (rule #20).
    const unsigned long long lt = (lane == 0) ? 0ull : ((~0ull) >> (64 - lane));
    #pragma unroll
    for (int r = 0; r < 4; ++r){
        const int lrow = r0 + wrow + r;
        const float xi = xs[lrow];
        unsigned u[16];
        #pragma unroll
        for (int q = 0; q < 16; ++q){
            float d = 2.f*acc[r][q] - xi - xs[lane + 64*q];
            unsigned bits = __float_as_uint(d);
            unsigned m = (bits & 0x80000000u) ? 0xFFFFFFFFu : 0x80000000u;
            u[q] = bits ^ m;
        }
        unsigned t = 0u;
        for (int bb = 31; bb >= 0; --bb){
            unsigned cand = t | (1u << bb);
            int cnt = 0;
            #pragma unroll
            for (int q = 0; q < 16; ++q)
                cnt += (int)__popcll(__ballot(u[q] >= cand));
            if (cnt >= KNNK) t = cand;
        }
        int* orow = idxout + ((size_t)b*NN + lrow) * KNNK;
        int cbase = 0;
        #pragma unroll
        for (int q = 0; q < 16; ++q){
            bool gt2 = (u[q] > t);
            unsigned long long mask = __ballot(gt2);
            if (gt2) orow[cbase + (int)__popcll(mask & lt)] = q*64 + lane;
            cbase += (int)__popcll(mask);
        }
        #pragma unroll
        for (int q = 0; q < 16; ++q){
            bool eq = (u[q] == t);
            unsigned long long mask = __ballot(eq);
            int pos = cbase + (int)__popcll(mask & lt);
            if (eq && pos < KNNK) orow[pos] = q*64 + lane;
            cbase += (int)__popcll(mask);
        }
    }
}

// ---------------- G GEMMs: G1 = X @ W[:, :C]^T ; Gd = X @ (W[:,C:]-W[:, :C])^T ----------------
template<int C, int O>
__global__ void __launch_bounds__(256) gemmG_kernel(const float* __restrict__ x, int stride,
                                                    const float* __restrict__ W,
                                                    float* __restrict__ G1, float* __restrict__ Gd){
    constexpr int KC = (C < 32 ? C : 32);
    __shared__ float Xl [KC][68];
    __shared__ float W1l[KC][68];
    __shared__ float W2l[KC][68];
    const int tid = threadIdx.x;
    const int r0 = blockIdx.x * 64;
    const int o0 = blockIdx.y * 64;
    const int rt = tid & 15, ct = tid >> 4;

    float a1[4][4] = {{0.f}}, a2[4][4] = {{0.f}};
    for (int kc = 0; kc < C; kc += KC){
        __syncthreads();
        for (int i = tid; i < KC*64; i += 256){
            int k = i % KC, rr = i / KC;
            Xl [k][rr] = x[(size_t)(r0+rr)*stride + kc + k];
            W1l[k][rr] = W[(size_t)(o0+rr)*(2*C) + kc + k];
            W2l[k][rr] = W[(size_t)(o0+rr)*(2*C) + C + kc + k];
        }
        __syncthreads();
        #pragma unroll
        for (int k = 0; k < KC; ++k){
            float4 xa = *(const float4*)&Xl [k][rt*4];
            float4 w1 = *(const float4*)&W1l[k][ct*4];
            float4 w2 = *(const float4*)&W2l[k][ct*4];
            float xv[4] = {xa.x, xa.y, xa.z, xa.w};
            #pragma unroll
            for (int i = 0; i < 4; ++i){
                a1[i][0] = fmaf(xv[i], w1.x, a1[i][0]);
                a1[i][1] = fmaf(xv[i], w1.y, a1[i][1]);
                a1[i][2] = fmaf(xv[i], w1.z, a1[i][2]);
                a1[i][3] = fmaf(xv[i], w1.w, a1[i][3]);
                a2[i][0] = fmaf(xv[i], w2.x, a2[i][0]);
                a2[i][1] = fmaf(xv[i], w2.y, a2[i][1]);
                a2[i][2] = fmaf(xv[i], w2.z, a2[i][2]);
                a2[i][3] = fmaf(xv[i], w2.w, a2[i][3]);
            }
        }
    }
    #pragma unroll
    for (int i = 0; i < 4; ++i){
        size_t row = (size_t)(r0 + rt*4 + i);
        float4 g1v = make_float4(a1[i][0], a1[i][1], a1[i][2], a1[i][3]);
        float4 gdv = make_float4(a2[i][0]-a1[i][0], a2[i][1]-a1[i][1],
                                 a2[i][2]-a1[i][2], a2[i][3]-a1[i][3]);
        *(float4*)&G1[row*O + o0 + ct*4] = g1v;
        *(float4*)&Gd[row*O + o0 + ct*4] = gdv;
    }
}

// ---------------- gather (float4): per (point, 4 cols) max/sum/sumsq over k ----------------
template<int O>
__global__ void __launch_bounds__(256) gather_kernel(const float* __restrict__ G1,
                                                     const float* __restrict__ Gd,
                                                     const int* __restrict__ idxg, int bgbase,
                                                     float* __restrict__ catslice,
                                                     float* __restrict__ stats){
    constexpr int OG = O/4;
    constexpr int PP = 256/OG;
    constexpr int NP = 16;
    __shared__ int nbs[NP][KNNK];
    const int nwg = (int)gridDim.x;
    int bid = (int)blockIdx.x;
    if ((nwg & 7) == 0){
        const int cpx = nwg >> 3;
        bid = (bid & 7) * cpx + (bid >> 3);
    }
    const int tid = threadIdx.x;
    const int p0 = bid * NP;
    for (int i = tid; i < NP*KNNK; i += 256){
        int pp = i / KNNK, kk = i - pp*KNNK;
        int pl = p0 + pp;
        nbs[pp][kk] = ((pl >> 10) << 10) + idxg[(size_t)(bgbase + pl)*KNNK + kk];
    }
    __syncthreads();
    const int o4 = (tid % OG)*4;
    const int pq = tid / OG;
    float S1[4] = {0.f,0.f,0.f,0.f}, S2[4] = {0.f,0.f,0.f,0.f};
    for (int pp = pq; pp < NP; pp += PP){
        int pl = p0 + pp;
        float4 dv = *(const float4*)&Gd[(size_t)pl*O + o4];
        float d[4] = {dv.x, dv.y, dv.z, dv.w};
        float mx[4] = {-INFINITY,-INFINITY,-INFINITY,-INFINITY};
        float ls[4] = {0.f,0.f,0.f,0.f}, lq[4] = {0.f,0.f,0.f,0.f};
        #pragma unroll
        for (int kk = 0; kk < KNNK; ++kk){
            float4 gv = *(const float4*)&G1[(size_t)nbs[pp][kk]*O + o4];
            float ga[4] = {gv.x, gv.y, gv.z, gv.w};
            #pragma unroll
            for (int c = 0; c < 4; ++c){
                mx[c] = fmaxf(mx[c], ga[c]);
                ls[c] += ga[c];
                lq[c] = fmaf(ga[c], ga[c], lq[c]);
            }
        }
        float4 outv;
        float* op = &outv.x;
        #pragma unroll
        for (int c = 0; c < 4; ++c){
            S1[c] += ls[c] + 20.f*d[c];
            S2[c] += lq[c] + 2.f*d[c]*ls[c] + 20.f*d[c]*d[c];
            op[c] = mx[c] + d[c];
        }
        *(float4*)&catslice[(size_t)(bgbase + pl)*512 + o4] = outv;
    }
    int rep = bid & 63;
    #pragma unroll
    for (int c = 0; c < 4; ++c){
        atomicAdd(&stats[rep*2*O + o4 + c],     S1[c]);
        atomicAdd(&stats[rep*2*O + O + o4 + c], S2[c]);
    }
}

// ---------------- finalize BN stats ----------------
__global__ void fin_kernel(const float* __restrict__ stats, int O, float cnt,
                           float* __restrict__ mean, float* __restrict__ invstd){
    int o = threadIdx.x;
    if (o >= O) return;
    float s1 = 0.f, s2 = 0.f;
    for (int r = 0; r < 64; ++r){
        s1 += stats[r*2*O + o];
        s2 += stats[r*2*O + O + o];
    }
    float m = s1 / cnt;
    float v = s2 / cnt - m*m;
    mean[o] = m;
    invstd[o] = rsqrtf(v + 1e-5f);
}

// ---------------- apply BN+LReLU in place on cat slice ----------------
template<int O>
__global__ void apply_kernel(float* __restrict__ catslice,
                             const float* __restrict__ mean, const float* __restrict__ invstd,
                             const float* __restrict__ g, const float* __restrict__ bt){
    int i = blockIdx.x*256 + threadIdx.x;
    int pn = i / O, o = i - pn*O;
    float* p = &catslice[(size_t)pn*512 + o];
    float hn = (*p - mean[o]) * invstd[o] * g[o] + bt[o];
    *p = lrelu(hn);
}

// ---------------- fp32 -> bf16 conversion (4 elems/thread) ----------------
__global__ void tob16_kernel(const float* __restrict__ src, unsigned short* __restrict__ dst, int n4){
    int i = blockIdx.x*256 + threadIdx.x;
    if (i >= n4) return;
    float4 v = *(const float4*)&src[(size_t)i*4];
    ushort4 o;
    o.x = f2b(v.x); o.y = f2b(v.y); o.z = f2b(v.z); o.w = f2b(v.w);
    *(ushort4*)&dst[(size_t)i*4] = o;
}

// ---------------- layer 5 MFMA: 32x32x16 frags, 64x64/wave, 128x128/block ----------------
__global__ void __launch_bounds__(256) l5m_kernel(const unsigned short* __restrict__ Am,
                                                  const unsigned short* __restrict__ Bm,
                                                  float* __restrict__ pmax,
                                                  float* __restrict__ psum,
                                                  float* __restrict__ psq){
    __shared__ __align__(16) unsigned short As[128][64];
    __shared__ __align__(16) unsigned short Bs[128][64];
    const int tid = threadIdx.x;
    const int r0 = blockIdx.x * 128;
    const int o0 = blockIdx.y * 128;
    const int w = tid >> 6, lane = tid & 63;
    const int m32 = lane & 31, kh = lane >> 5;
    const int wm = (w & 1) * 64;
    const int wn = (w >> 1) * 64;

    f32x16 acc[2][2];
    #pragma unroll
    for (int i=0;i<2;++i)
        #pragma unroll
        for (int j=0;j<2;++j)
            #pragma unroll
            for (int r=0;r<16;++r) acc[i][j][r] = 0.f;

    for (int kc = 0; kc < 512; kc += 64){
        __syncthreads();
        #pragma unroll
        for (int t = 0; t < 4; ++t){
            int i = tid + t*256;
            int rr = i >> 3, ch = i & 7;
            int sl = ch ^ (rr & 7);
            *(uint4*)&As[rr][sl*8] = *(const uint4*)&Am[(size_t)(r0+rr)*512 + kc + ch*8];
            *(uint4*)&Bs[rr][sl*8] = *(const uint4*)&Bm[(size_t)(o0+rr)*512 + kc + ch*8];
        }
        __syncthreads();
        #pragma unroll
        for (int q = 0; q < 4; ++q){
            int lk = q*2 + kh;
            short8 a[2], bfr[2];
            #pragma unroll
            for (int mb = 0; mb < 2; ++mb){
                int rA = wm + mb*32 + m32;
                a[mb] = *(const short8*)&As[rA][(lk ^ (rA & 7))*8];
            }
            #pragma unroll
            for (int nb = 0; nb < 2; ++nb){
                int rB = wn + nb*32 + m32;
                bfr[nb] = *(const short8*)&Bs[rB][(lk ^ (rB & 7))*8];
            }
            #pragma unroll
            for (int mb = 0; mb < 2; ++mb)
                #pragma unroll
                for (int nb = 0; nb < 2; ++nb)
                    acc[mb][nb] = __builtin_amdgcn_mfma_f32_32x32x16_bf16(a[mb], bfr[nb], acc[mb][nb], 0, 0, 0);
        }
    }
    __syncthreads();
    float* red = (float*)&As[0][0];
    #pragma unroll
    for (int nb = 0; nb < 2; ++nb){
        float mx = -INFINITY, s1 = 0.f, s2 = 0.f;
        #pragma unroll
        for (int mb = 0; mb < 2; ++mb)
            #pragma unroll
            for (int r = 0; r < 16; ++r){
                float v = acc[mb][nb][r];
                mx = fmaxf(mx, v); s1 += v; s2 = fmaf(v, v, s2);
            }
        mx = fmaxf(mx, __shfl_xor(mx, 32));
        s1 += __shfl_xor(s1, 32);
        s2 += __shfl_xor(s2, 32);
        if (lane < 32){
            int col = wn + nb*32 + m32;
            float* p = red + ((size_t)(w & 1) * 128 + col) * 3;
            p[0] = mx; p[1] = s1; p[2] = s2;
        }
    }
    __syncthreads();
    if (tid < 128){
        const float* p0 = red + (size_t)tid*3;
        const float* p1 = red + (size_t)(128 + tid)*3;
        float mx = fmaxf(p0[0], p1[0]);
        float s1 = p0[1] + p1[1];
        float s2 = p0[2] + p1[2];
        size_t pi = (size_t)blockIdx.x*1024 + o0 + tid;
        pmax[pi] = mx; psum[pi] = s1; psq[pi] = s2;
    }
}

__global__ void fin5_kernel(const float* __restrict__ pmax, const float* __restrict__ psum,
                            const float* __restrict__ psq,
                            const float* __restrict__ g, const float* __restrict__ bt,
                            float* __restrict__ out){
    int o = blockIdx.x*256 + threadIdx.x; // 1024 total
    float s1 = 0.f, s2 = 0.f;
    for (int r = 0; r < 256; ++r){
        s1 += psum[(size_t)r*1024 + o];
        s2 += psq [(size_t)r*1024 + o];
    }
    float m  = s1 / 32768.f;
    float v  = s2 / 32768.f - m*m;
    float is = rsqrtf(v + 1e-5f);
    float gg = g[o], bb2 = bt[o];
    for (int b = 0; b < 32; ++b){
        float mx = -INFINITY;
        #pragma unroll
        for (int ns = 0; ns < 8; ++ns) mx = fmaxf(mx, pmax[((size_t)b*8 + ns)*1024 + o]);
        float hn = (mx - m) * is * gg + bb2;
        out[(size_t)b*1024 + o] = lrelu(hn);
    }
}

extern "C" void kernel_launch(void* const* d_in, const int* in_sizes, int n_in,
                              void* d_out, int out_size, void* d_ws, size_t ws_size,
                              hipStream_t stream) {
    (void)in_sizes; (void)n_in; (void)out_size;
    const float* x  = (const float*)d_in[0];
    const float* W1 = (const float*)d_in[1];  const float* g1 = (const float*)d_in[2];  const float* b1 = (const float*)d_in[3];
    const float* W2 = (const float*)d_in[4];  const float* g2 = (const float*)d_in[5];  const float* b2 = (const float*)d_in[6];
    const float* W3 = (const float*)d_in[7];  const float* g3 = (const float*)d_in[8];  const float* b3 = (const float*)d_in[9];
    const float* W4 = (const float*)d_in[10]; const float* g4 = (const float*)d_in[11]; const float* b4 = (const float*)d_in[12];
    const float* W5 = (const float*)d_in[13]; const float* g5 = (const float*)d_in[14]; const float* b5 = (const float*)d_in[15];
    float* out = (float*)d_out;

    const size_t fixedBytes = (size_t)PTS*512*4 + (size_t)PTS*KNNK*4 + (size_t)PTS*4
                            + (size_t)64*2*256*4 + 2048*4 + 3*(size_t)256*1024*4
                            + (size_t)1024*512*2;
    int CB;
    if      (ws_size >= fixedBytes + (size_t)32*NN*NN*4) CB = 32;
    else if (ws_size >= fixedBytes + (size_t)16*NN*NN*4) CB = 16;
    else                                                 CB = 8;
    const size_t Rbytes = (size_t)CB*NN*NN*4;

    char* wsp = (char*)d_ws;
    float* cat    = (float*)wsp; wsp += (size_t)PTS*512*4;
    char*  R      = wsp;         wsp += Rbytes;
    int*   idx    = (int*)  wsp; wsp += (size_t)PTS*KNNK*4;
    float* xx     = (float*)wsp; wsp += (size_t)PTS*4;
    float* stats  = (float*)wsp; wsp += (size_t)64*2*256*4;
    float* mean   = (float*)wsp; wsp += 1024*4;
    float* invstd = (float*)wsp; wsp += 1024*4;
    float* pmax   = (float*)wsp; wsp += (size_t)256*1024*4;
    float* psum   = (float*)wsp; wsp += (size_t)256*1024*4;
    float* psq    = (float*)wsp; wsp += (size_t)256*1024*4;
    unsigned short* W5b = (unsigned short*)wsp; wsp += (size_t)1024*512*2;

    float* G1    = (float*)R;
    float* GdS   = (float*)(R + (size_t)16*1024*1024);
    float* GdB   = (float*)(R + (size_t)32*1024*1024);
    unsigned short* catB = (unsigned short*)R;

    const float cntE = (float)(PTS*KNNK);
    const bool bigG = (Rbytes >= (size_t)64*1024*1024);

    // ---- Layer 1: C=3 -> O=64 ----
    sq_kernel<<<PTS/256, 256, 0, stream>>>(x, 3, 3, xx);
    knn_kernel<3><<<1024, 512, 0, stream>>>(x, 3, xx, idx);
    hipMemsetAsync(stats, 0, 64*2*256*4, stream);
    gemmG_kernel<3,64><<<dim3(512,1), 256, 0, stream>>>(x, 3, W1, G1, GdS);
    gather_kernel<64><<<2048, 256, 0, stream>>>(G1, GdS, idx, 0, cat + 0, stats);
    fin_kernel<<<1, 64, 0, stream>>>(stats, 64, cntE, mean, invstd);
    apply_kernel<64><<<PTS*64/256, 256, 0, stream>>>(cat + 0, mean, invstd, g1, b1);

    // ---- Layer 2: C=64 -> O=64 ----
    sq_kernel<<<PTS/256, 256, 0, stream>>>(cat + 0, 512, 64, xx);
    knn_kernel<64><<<1024, 512, 0, stream>>>(cat + 0, 512, xx, idx);
    hipMemsetAsync(stats, 0, 64*2*256*4, stream);
    gemmG_kernel<64,64><<<dim3(512,1), 256, 0, stream>>>(cat + 0, 512, W2, G1, GdS);
    gather_kernel<64><<<2048, 256, 0, stream>>>(G1, GdS, idx, 0, cat + 64, stats);
    fin_kernel<<<1, 64, 0, stream>>>(stats, 64, cntE, mean, invstd);
    apply_kernel<64><<<PTS*64/256, 256, 0, stream>>>(cat + 64, mean, invstd, g2, b2);

    // ---- Layer 3: C=64 -> O=128 ----
    sq_kernel<<<PTS/256, 256, 0, stream>>>(cat + 64, 512, 64, xx);
    knn_kernel<64><<<1024, 512, 0, stream>>>(cat + 64, 512, xx, idx);
    hipMemsetAsync(stats, 0, 64*2*256*4, stream);
    gemmG_kernel<64,128><<<dim3(512,2), 256, 0, stream>>>(cat + 64, 512, W3, G1, GdS);
    gather_kernel<128><<<2048, 256, 0, stream>>>(G1, GdS, idx, 0, cat + 128, stats);
    fin_kernel<<<1, 128, 0, stream>>>(stats, 128, cntE, mean, invstd);
    apply_kernel<128><<<PTS*128/256, 256, 0, stream>>>(cat + 128, mean, invstd, g3, b3);

    // ---- Layer 4: C=128 -> O=256 ----
    sq_kernel<<<PTS/256, 256, 0, stream>>>(cat + 128, 512, 128, xx);
    knn_kernel<128><<<1024, 512, 0, stream>>>(cat + 128, 512, xx, idx);
    hipMemsetAsync(stats, 0, 64*2*256*4, stream);
    if (bigG){
        gemmG_kernel<128,256><<<dim3(512,4), 256, 0, stream>>>(cat + 128, 512, W4, G1, GdB);
        gather_kernel<256><<<2048, 256, 0, stream>>>(G1, GdB, idx, 0, cat + 256, stats);
    } else {
        for (int bg = 0; bg < 4; ++bg){
            gemmG_kernel<128,256><<<dim3(128,4), 256, 0, stream>>>(cat + 128 + (size_t)bg*8192*512, 512, W4, G1, GdS);
            gather_kernel<256><<<512, 256, 0, stream>>>(G1, GdS, idx, bg*8192, cat + 256, stats);
        }
    }
    fin_kernel<<<1, 256, 0, stream>>>(stats, 256, cntE, mean, invstd);
    apply_kernel<256><<<PTS*256/256, 256, 0, stream>>>(cat + 256, mean, invstd, g4, b4);

    // ---- Layer 5: bf16 MFMA GEMM with fused max/stats ----
    tob16_kernel<<<PTS*512/4/256, 256, 0, stream>>>(cat, catB, PTS*512/4);
    tob16_kernel<<<1024*512/4/256, 256, 0, stream>>>(W5, W5b, 1024*512/4);
    l5m_kernel<<<dim3(256, 8), 256, 0, stream>>>(catB, W5b, pmax, psum, psq);
    fin5_kernel<<<4, 256, 0, stream>>>(pmax, psum, psq, g5, b5, out);
}

// Round 4
// 1331.037 us; speedup vs baseline: 2.3534x; 1.0291x over previous
//
#include <hip/hip_runtime.h>
#include <math.h>

#define BB 32
#define NN 1024
#define KNNK 20
#define PTS (BB*NN)   // 32768

typedef __attribute__((ext_vector_type(8)))  short short8;
typedef __attribute__((ext_vector_type(4)))  float f32x4;
typedef __attribute__((ext_vector_type(16))) float f32x16;

__device__ __forceinline__ float lrelu(float v){ return v >= 0.f ? v : 0.2f*v; }

__device__ __forceinline__ unsigned short f2b(float x){
    union { float f; unsigned u; } c; c.f = x;
    unsigned r = c.u + 0x7FFFu + ((c.u >> 16) & 1u);
    return (unsigned short)(r >> 16);
}

// ---------------- squared norms per point ----------------
__global__ void sq_kernel(const float* __restrict__ x, int stride, int C, float* __restrict__ xx){
    int pn = blockIdx.x*256 + threadIdx.x;
    if (pn >= PTS) return;
    const float* r = x + (size_t)pn*stride;
    float s = 0.f;
    if ((C & 3) == 0){
        for (int c = 0; c < C; c += 4){
            float4 v = *(const float4*)&r[c];
            s = fmaf(v.x, v.x, s); s = fmaf(v.y, v.y, s);
            s = fmaf(v.z, v.z, s); s = fmaf(v.w, v.w, s);
        }
    } else {
        for (int c = 0; c < C; ++c){ float v = r[c]; s = fmaf(v, v, s); }
    }
    xx[pn] = s;
}

// ---------------- FUSED knn: distance GEMM + radix-bisection top-20, no D matrix ----------------
// 512 threads = 8 waves x 4 rows -> 32 rows/block, 1024 blocks. acc[4][16] = 64 VGPRs.
// LDS layout Bs[granule][col][4]: bv read = 64 lanes contiguous 16B each -> canonical
// conflict-free ds_read_b128. (Round-3 layout [col][8] put lane l at byte l*32 -> 4 banks
// -> 16-way conflict on the op feeding every 16 FMAs; 16.8M conflict cycles, 228us.)
// ar reads are wave-broadcast (free). k-granule order s=0 then s=1, x..w within ->
// FMA order identical to the passing version -> bit-identical distances.
// Epilogue fully unrolled (rule #20: no runtime indexing of acc/u).
template<int C>
__global__ void __launch_bounds__(512, 4) knn_kernel(const float* __restrict__ x, int stride,
                                                     const float* __restrict__ xx,
                                                     int* __restrict__ idxout){
    constexpr int KC = 8;
    __shared__ __align__(16) float Bs[2][NN][4];   // 32 KB: [k-granule][col][4]
    __shared__ float xs[NN];                       // 4 KB
    // XCD-chunked swizzle: each XCD gets 4 whole batches (B slice L2-resident).
    int bid = (int)blockIdx.x;
    bid = (bid & 7)*128 + (bid >> 3);
    const int b  = bid >> 5;
    const int rb = bid & 31;
    const int r0 = rb * 32;
    const int tid = threadIdx.x;
    const int wv = tid >> 6, lane = tid & 63;
    const float* xb = x + (size_t)b*NN*stride;

    if (tid < 256) *(float4*)&xs[tid*4] = *(const float4*)&xx[b*NN + tid*4];

    float acc[4][16];
    #pragma unroll
    for (int r=0;r<4;++r)
        #pragma unroll
        for (int q=0;q<16;++q) acc[r][q] = 0.f;

    const int wrow = wv*4;          // wave's first local row

    #pragma unroll 1
    for (int kc = 0; kc < C; kc += KC){
        __syncthreads();
        // stage B chunk: i -> (col = i>>1, half = i&1), 4 passes of float4 (512 thr)
        #pragma unroll
        for (int ps = 0; ps < 4; ++ps){
            int i = tid + ps*512;             // 0..2047
            int col = i >> 1, half = i & 1;
            float4 v;
            if constexpr (C == 3){
                float vv[4];
                #pragma unroll
                for (int j = 0; j < 4; ++j){
                    int k = half*4 + j;
                    vv[j] = (k < 3) ? xb[(size_t)col*3 + k] : 0.f;
                }
                v = make_float4(vv[0], vv[1], vv[2], vv[3]);
            } else {
                v = *(const float4*)&xb[(size_t)col*stride + kc + half*4];
            }
            *(float4*)&Bs[half][col][0] = v;
        }
        __syncthreads();
        #pragma unroll
        for (int s = 0; s < 2; ++s){          // two 4-k granules
            float4 ar[4];
            #pragma unroll
            for (int r=0;r<4;++r)
                ar[r] = *(const float4*)&Bs[s][r0 + wrow + r][0];   // broadcast
            #pragma unroll
            for (int q=0;q<16;++q){
                float4 bv = *(const float4*)&Bs[s][lane + 64*q][0]; // contiguous
                #pragma unroll
                for (int r=0;r<4;++r){
                    acc[r][q] = fmaf(ar[r].x, bv.x, acc[r][q]);
                    acc[r][q] = fmaf(ar[r].y, bv.y, acc[r][q]);
                    acc[r][q] = fmaf(ar[r].z, bv.z, acc[r][q]);
                    acc[r][q] = fmaf(ar[r].w, bv.w, acc[r][q]);
                }
            }
        }
    }

    // ---- per-row epilogue: distance map + radix bisection + ballot emission ----
    const unsigned long long lt = (lane == 0) ? 0ull : ((~0ull) >> (64 - lane));
    #pragma unroll
    for (int r = 0; r < 4; ++r){
        const int lrow = r0 + wrow + r;
        const float xi = xs[lrow];
        unsigned u[16];
        #pragma unroll
        for (int q = 0; q < 16; ++q){
            float d = 2.f*acc[r][q] - xi - xs[lane + 64*q];
            unsigned bits = __float_as_uint(d);
            unsigned m = (bits & 0x80000000u) ? 0xFFFFFFFFu : 0x80000000u;
            u[q] = bits ^ m;
        }
        unsigned t = 0u;
        for (int bb = 31; bb >= 0; --bb){
            unsigned cand = t | (1u << bb);
            int cnt = 0;
            #pragma unroll
            for (int q = 0; q < 16; ++q)
                cnt += (int)__popcll(__ballot(u[q] >= cand));
            if (cnt >= KNNK) t = cand;
        }
        int* orow = idxout + ((size_t)b*NN + lrow) * KNNK;
        int cbase = 0;
        #pragma unroll
        for (int q = 0; q < 16; ++q){
            bool gt2 = (u[q] > t);
            unsigned long long mask = __ballot(gt2);
            if (gt2) orow[cbase + (int)__popcll(mask & lt)] = q*64 + lane;
            cbase += (int)__popcll(mask);
        }
        #pragma unroll
        for (int q = 0; q < 16; ++q){
            bool eq = (u[q] == t);
            unsigned long long mask = __ballot(eq);
            int pos = cbase + (int)__popcll(mask & lt);
            if (eq && pos < KNNK) orow[pos] = q*64 + lane;
            cbase += (int)__popcll(mask);
        }
    }
}

// ---------------- G GEMMs: G1 = X @ W[:, :C]^T ; Gd = X @ (W[:,C:]-W[:, :C])^T ----------------
template<int C, int O>
__global__ void __launch_bounds__(256) gemmG_kernel(const float* __restrict__ x, int stride,
                                                    const float* __restrict__ W,
                                                    float* __restrict__ G1, float* __restrict__ Gd){
    constexpr int KC = (C < 32 ? C : 32);
    __shared__ float Xl [KC][68];
    __shared__ float W1l[KC][68];
    __shared__ float W2l[KC][68];
    const int tid = threadIdx.x;
    const int r0 = blockIdx.x * 64;
    const int o0 = blockIdx.y * 64;
    const int rt = tid & 15, ct = tid >> 4;

    float a1[4][4] = {{0.f}}, a2[4][4] = {{0.f}};
    for (int kc = 0; kc < C; kc += KC){
        __syncthreads();
        for (int i = tid; i < KC*64; i += 256){
            int k = i % KC, rr = i / KC;
            Xl [k][rr] = x[(size_t)(r0+rr)*stride + kc + k];
            W1l[k][rr] = W[(size_t)(o0+rr)*(2*C) + kc + k];
            W2l[k][rr] = W[(size_t)(o0+rr)*(2*C) + C + kc + k];
        }
        __syncthreads();
        #pragma unroll
        for (int k = 0; k < KC; ++k){
            float4 xa = *(const float4*)&Xl [k][rt*4];
            float4 w1 = *(const float4*)&W1l[k][ct*4];
            float4 w2 = *(const float4*)&W2l[k][ct*4];
            float xv[4] = {xa.x, xa.y, xa.z, xa.w};
            #pragma unroll
            for (int i = 0; i < 4; ++i){
                a1[i][0] = fmaf(xv[i], w1.x, a1[i][0]);
                a1[i][1] = fmaf(xv[i], w1.y, a1[i][1]);
                a1[i][2] = fmaf(xv[i], w1.z, a1[i][2]);
                a1[i][3] = fmaf(xv[i], w1.w, a1[i][3]);
                a2[i][0] = fmaf(xv[i], w2.x, a2[i][0]);
                a2[i][1] = fmaf(xv[i], w2.y, a2[i][1]);
                a2[i][2] = fmaf(xv[i], w2.z, a2[i][2]);
                a2[i][3] = fmaf(xv[i], w2.w, a2[i][3]);
            }
        }
    }
    #pragma unroll
    for (int i = 0; i < 4; ++i){
        size_t row = (size_t)(r0 + rt*4 + i);
        float4 g1v = make_float4(a1[i][0], a1[i][1], a1[i][2], a1[i][3]);
        float4 gdv = make_float4(a2[i][0]-a1[i][0], a2[i][1]-a1[i][1],
                                 a2[i][2]-a1[i][2], a2[i][3]-a1[i][3]);
        *(float4*)&G1[row*O + o0 + ct*4] = g1v;
        *(float4*)&Gd[row*O + o0 + ct*4] = gdv;
    }
}

// ---------------- gather (float4): per (point, 4 cols) max/sum/sumsq over k ----------------
template<int O>
__global__ void __launch_bounds__(256) gather_kernel(const float* __restrict__ G1,
                                                     const float* __restrict__ Gd,
                                                     const int* __restrict__ idxg, int bgbase,
                                                     float* __restrict__ catslice,
                                                     float* __restrict__ stats){
    constexpr int OG = O/4;
    constexpr int PP = 256/OG;
    constexpr int NP = 16;
    __shared__ int nbs[NP][KNNK];
    const int nwg = (int)gridDim.x;
    int bid = (int)blockIdx.x;
    if ((nwg & 7) == 0){
        const int cpx = nwg >> 3;
        bid = (bid & 7) * cpx + (bid >> 3);
    }
    const int tid = threadIdx.x;
    const int p0 = bid * NP;
    for (int i = tid; i < NP*KNNK; i += 256){
        int pp = i / KNNK, kk = i - pp*KNNK;
        int pl = p0 + pp;
        nbs[pp][kk] = ((pl >> 10) << 10) + idxg[(size_t)(bgbase + pl)*KNNK + kk];
    }
    __syncthreads();
    const int o4 = (tid % OG)*4;
    const int pq = tid / OG;
    float S1[4] = {0.f,0.f,0.f,0.f}, S2[4] = {0.f,0.f,0.f,0.f};
    for (int pp = pq; pp < NP; pp += PP){
        int pl = p0 + pp;
        float4 dv = *(const float4*)&Gd[(size_t)pl*O + o4];
        float d[4] = {dv.x, dv.y, dv.z, dv.w};
        float mx[4] = {-INFINITY,-INFINITY,-INFINITY,-INFINITY};
        float ls[4] = {0.f,0.f,0.f,0.f}, lq[4] = {0.f,0.f,0.f,0.f};
        #pragma unroll
        for (int kk = 0; kk < KNNK; ++kk){
            float4 gv = *(const float4*)&G1[(size_t)nbs[pp][kk]*O + o4];
            float ga[4] = {gv.x, gv.y, gv.z, gv.w};
            #pragma unroll
            for (int c = 0; c < 4; ++c){
                mx[c] = fmaxf(mx[c], ga[c]);
                ls[c] += ga[c];
                lq[c] = fmaf(ga[c], ga[c], lq[c]);
            }
        }
        float4 outv;
        float* op = &outv.x;
        #pragma unroll
        for (int c = 0; c < 4; ++c){
            S1[c] += ls[c] + 20.f*d[c];
            S2[c] += lq[c] + 2.f*d[c]*ls[c] + 20.f*d[c]*d[c];
            op[c] = mx[c] + d[c];
        }
        *(float4*)&catslice[(size_t)(bgbase + pl)*512 + o4] = outv;
    }
    int rep = bid & 63;
    #pragma unroll
    for (int c = 0; c < 4; ++c){
        atomicAdd(&stats[rep*2*O + o4 + c],     S1[c]);
        atomicAdd(&stats[rep*2*O + O + o4 + c], S2[c]);
    }
}

// ---------------- finalize BN stats ----------------
__global__ void fin_kernel(const float* __restrict__ stats, int O, float cnt,
                           float* __restrict__ mean, float* __restrict__ invstd){
    int o = threadIdx.x;
    if (o >= O) return;
    float s1 = 0.f, s2 = 0.f;
    for (int r = 0; r < 64; ++r){
        s1 += stats[r*2*O + o];
        s2 += stats[r*2*O + O + o];
    }
    float m = s1 / cnt;
    float v = s2 / cnt - m*m;
    mean[o] = m;
    invstd[o] = rsqrtf(v + 1e-5f);
}

// ---------------- apply BN+LReLU in place on cat slice ----------------
template<int O>
__global__ void apply_kernel(float* __restrict__ catslice,
                             const float* __restrict__ mean, const float* __restrict__ invstd,
                             const float* __restrict__ g, const float* __restrict__ bt){
    int i = blockIdx.x*256 + threadIdx.x;
    int pn = i / O, o = i - pn*O;
    float* p = &catslice[(size_t)pn*512 + o];
    float hn = (*p - mean[o]) * invstd[o] * g[o] + bt[o];
    *p = lrelu(hn);
}

// ---------------- fp32 -> bf16 conversion (4 elems/thread) ----------------
__global__ void tob16_kernel(const float* __restrict__ src, unsigned short* __restrict__ dst, int n4){
    int i = blockIdx.x*256 + threadIdx.x;
    if (i >= n4) return;
    float4 v = *(const float4*)&src[(size_t)i*4];
    ushort4 o;
    o.x = f2b(v.x); o.y = f2b(v.y); o.z = f2b(v.z); o.w = f2b(v.w);
    *(ushort4*)&dst[(size_t)i*4] = o;
}

// ---------------- layer 5 MFMA: 32x32x16 frags, 64x64/wave, 128x128/block ----------------
__global__ void __launch_bounds__(256) l5m_kernel(const unsigned short* __restrict__ Am,
                                                  const unsigned short* __restrict__ Bm,
                                                  float* __restrict__ pmax,
                                                  float* __restrict__ psum,
                                                  float* __restrict__ psq){
    __shared__ __align__(16) unsigned short As[128][64];
    __shared__ __align__(16) unsigned short Bs[128][64];
    const int tid = threadIdx.x;
    const int r0 = blockIdx.x * 128;
    const int o0 = blockIdx.y * 128;
    const int w = tid >> 6, lane = tid & 63;
    const int m32 = lane & 31, kh = lane >> 5;
    const int wm = (w & 1) * 64;
    const int wn = (w >> 1) * 64;

    f32x16 acc[2][2];
    #pragma unroll
    for (int i=0;i<2;++i)
        #pragma unroll
        for (int j=0;j<2;++j)
            #pragma unroll
            for (int r=0;r<16;++r) acc[i][j][r] = 0.f;

    for (int kc = 0; kc < 512; kc += 64){
        __syncthreads();
        #pragma unroll
        for (int t = 0; t < 4; ++t){
            int i = tid + t*256;
            int rr = i >> 3, ch = i & 7;
            int sl = ch ^ (rr & 7);
            *(uint4*)&As[rr][sl*8] = *(const uint4*)&Am[(size_t)(r0+rr)*512 + kc + ch*8];
            *(uint4*)&Bs[rr][sl*8] = *(const uint4*)&Bm[(size_t)(o0+rr)*512 + kc + ch*8];
        }
        __syncthreads();
        #pragma unroll
        for (int q = 0; q < 4; ++q){
            int lk = q*2 + kh;
            short8 a[2], bfr[2];
            #pragma unroll
            for (int mb = 0; mb < 2; ++mb){
                int rA = wm + mb*32 + m32;
                a[mb] = *(const short8*)&As[rA][(lk ^ (rA & 7))*8];
            }
            #pragma unroll
            for (int nb = 0; nb < 2; ++nb){
                int rB = wn + nb*32 + m32;
                bfr[nb] = *(const short8*)&Bs[rB][(lk ^ (rB & 7))*8];
            }
            #pragma unroll
            for (int mb = 0; mb < 2; ++mb)
                #pragma unroll
                for (int nb = 0; nb < 2; ++nb)
                    acc[mb][nb] = __builtin_amdgcn_mfma_f32_32x32x16_bf16(a[mb], bfr[nb], acc[mb][nb], 0, 0, 0);
        }
    }
    __syncthreads();
    float* red = (float*)&As[0][0];
    #pragma unroll
    for (int nb = 0; nb < 2; ++nb){
        float mx = -INFINITY, s1 = 0.f, s2 = 0.f;
        #pragma unroll
        for (int mb = 0; mb < 2; ++mb)
            #pragma unroll
            for (int r = 0; r < 16; ++r){
                float v = acc[mb][nb][r];
                mx = fmaxf(mx, v); s1 += v; s2 = fmaf(v, v, s2);
            }
        mx = fmaxf(mx, __shfl_xor(mx, 32));
        s1 += __shfl_xor(s1, 32);
        s2 += __shfl_xor(s2, 32);
        if (lane < 32){
            int col = wn + nb*32 + m32;
            float* p = red + ((size_t)(w & 1) * 128 + col) * 3;
            p[0] = mx; p[1] = s1; p[2] = s2;
        }
    }
    __syncthreads();
    if (tid < 128){
        const float* p0 = red + (size_t)tid*3;
        const float* p1 = red + (size_t)(128 + tid)*3;
        float mx = fmaxf(p0[0], p1[0]);
        float s1 = p0[1] + p1[1];
        float s2 = p0[2] + p1[2];
        size_t pi = (size_t)blockIdx.x*1024 + o0 + tid;
        pmax[pi] = mx; psum[pi] = s1; psq[pi] = s2;
    }
}

__global__ void fin5_kernel(const float* __restrict__ pmax, const float* __restrict__ psum,
                            const float* __restrict__ psq,
                            const float* __restrict__ g, const float* __restrict__ bt,
                            float* __restrict__ out){
    int o = blockIdx.x*256 + threadIdx.x; // 1024 total
    float s1 = 0.f, s2 = 0.f;
    for (int r = 0; r < 256; ++r){
        s1 += psum[(size_t)r*1024 + o];
        s2 += psq [(size_t)r*1024 + o];
    }
    float m  = s1 / 32768.f;
    float v  = s2 / 32768.f - m*m;
    float is = rsqrtf(v + 1e-5f);
    float gg = g[o], bb2 = bt[o];
    for (int b = 0; b < 32; ++b){
        float mx = -INFINITY;
        #pragma unroll
        for (int ns = 0; ns < 8; ++ns) mx = fmaxf(mx, pmax[((size_t)b*8 + ns)*1024 + o]);
        float hn = (mx - m) * is * gg + bb2;
        out[(size_t)b*1024 + o] = lrelu(hn);
    }
}

extern "C" void kernel_launch(void* const* d_in, const int* in_sizes, int n_in,
                              void* d_out, int out_size, void* d_ws, size_t ws_size,
                              hipStream_t stream) {
    (void)in_sizes; (void)n_in; (void)out_size;
    const float* x  = (const float*)d_in[0];
    const float* W1 = (const float*)d_in[1];  const float* g1 = (const float*)d_in[2];  const float* b1 = (const float*)d_in[3];
    const float* W2 = (const float*)d_in[4];  const float* g2 = (const float*)d_in[5];  const float* b2 = (const float*)d_in[6];
    const float* W3 = (const float*)d_in[7];  const float* g3 = (const float*)d_in[8];  const float* b3 = (const float*)d_in[9];
    const float* W4 = (const float*)d_in[10]; const float* g4 = (const float*)d_in[11]; const float* b4 = (const float*)d_in[12];
    const float* W5 = (const float*)d_in[13]; const float* g5 = (const float*)d_in[14]; const float* b5 = (const float*)d_in[15];
    float* out = (float*)d_out;

    const size_t fixedBytes = (size_t)PTS*512*4 + (size_t)PTS*KNNK*4 + (size_t)PTS*4
                            + (size_t)64*2*256*4 + 2048*4 + 3*(size_t)256*1024*4
                            + (size_t)1024*512*2;
    int CB;
    if      (ws_size >= fixedBytes + (size_t)32*NN*NN*4) CB = 32;
    else if (ws_size >= fixedBytes + (size_t)16*NN*NN*4) CB = 16;
    else                                                 CB = 8;
    const size_t Rbytes = (size_t)CB*NN*NN*4;

    char* wsp = (char*)d_ws;
    float* cat    = (float*)wsp; wsp += (size_t)PTS*512*4;
    char*  R      = wsp;         wsp += Rbytes;
    int*   idx    = (int*)  wsp; wsp += (size_t)PTS*KNNK*4;
    float* xx     = (float*)wsp; wsp += (size_t)PTS*4;
    float* stats  = (float*)wsp; wsp += (size_t)64*2*256*4;
    float* mean   = (float*)wsp; wsp += 1024*4;
    float* invstd = (float*)wsp; wsp += 1024*4;
    float* pmax   = (float*)wsp; wsp += (size_t)256*1024*4;
    float* psum   = (float*)wsp; wsp += (size_t)256*1024*4;
    float* psq    = (float*)wsp; wsp += (size_t)256*1024*4;
    unsigned short* W5b = (unsigned short*)wsp; wsp += (size_t)1024*512*2;

    float* G1    = (float*)R;
    float* GdS   = (float*)(R + (size_t)16*1024*1024);
    float* GdB   = (float*)(R + (size_t)32*1024*1024);
    unsigned short* catB = (unsigned short*)R;

    const float cntE = (float)(PTS*KNNK);
    const bool bigG = (Rbytes >= (size_t)64*1024*1024);

    // ---- Layer 1: C=3 -> O=64 ----
    sq_kernel<<<PTS/256, 256, 0, stream>>>(x, 3, 3, xx);
    knn_kernel<3><<<1024, 512, 0, stream>>>(x, 3, xx, idx);
    hipMemsetAsync(stats, 0, 64*2*256*4, stream);
    gemmG_kernel<3,64><<<dim3(512,1), 256, 0, stream>>>(x, 3, W1, G1, GdS);
    gather_kernel<64><<<2048, 256, 0, stream>>>(G1, GdS, idx, 0, cat + 0, stats);
    fin_kernel<<<1, 64, 0, stream>>>(stats, 64, cntE, mean, invstd);
    apply_kernel<64><<<PTS*64/256, 256, 0, stream>>>(cat + 0, mean, invstd, g1, b1);

    // ---- Layer 2: C=64 -> O=64 ----
    sq_kernel<<<PTS/256, 256, 0, stream>>>(cat + 0, 512, 64, xx);
    knn_kernel<64><<<1024, 512, 0, stream>>>(cat + 0, 512, xx, idx);
    hipMemsetAsync(stats, 0, 64*2*256*4, stream);
    gemmG_kernel<64,64><<<dim3(512,1), 256, 0, stream>>>(cat + 0, 512, W2, G1, GdS);
    gather_kernel<64><<<2048, 256, 0, stream>>>(G1, GdS, idx, 0, cat + 64, stats);
    fin_kernel<<<1, 64, 0, stream>>>(stats, 64, cntE, mean, invstd);
    apply_kernel<64><<<PTS*64/256, 256, 0, stream>>>(cat + 64, mean, invstd, g2, b2);

    // ---- Layer 3: C=64 -> O=128 ----
    sq_kernel<<<PTS/256, 256, 0, stream>>>(cat + 64, 512, 64, xx);
    knn_kernel<64><<<1024, 512, 0, stream>>>(cat + 64, 512, xx, idx);
    hipMemsetAsync(stats, 0, 64*2*256*4, stream);
    gemmG_kernel<64,128><<<dim3(512,2), 256, 0, stream>>>(cat + 64, 512, W3, G1, GdS);
    gather_kernel<128><<<2048, 256, 0, stream>>>(G1, GdS, idx, 0, cat + 128, stats);
    fin_kernel<<<1, 128, 0, stream>>>(stats, 128, cntE, mean, invstd);
    apply_kernel<128><<<PTS*128/256, 256, 0, stream>>>(cat + 128, mean, invstd, g3, b3);

    // ---- Layer 4: C=128 -> O=256 ----
    sq_kernel<<<PTS/256, 256, 0, stream>>>(cat + 128, 512, 128, xx);
    knn_kernel<128><<<1024, 512, 0, stream>>>(cat + 128, 512, xx, idx);
    hipMemsetAsync(stats, 0, 64*2*256*4, stream);
    if (bigG){
        gemmG_kernel<128,256><<<dim3(512,4), 256, 0, stream>>>(cat + 128, 512, W4, G1, GdB);
        gather_kernel<256><<<2048, 256, 0, stream>>>(G1, GdB, idx, 0, cat + 256, stats);
    } else {
        for (int bg = 0; bg < 4; ++bg){
            gemmG_kernel<128,256><<<dim3(128,4), 256, 0, stream>>>(cat + 128 + (size_t)bg*8192*512, 512, W4, G1, GdS);
            gather_kernel<256><<<512, 256, 0, stream>>>(G1, GdS, idx, bg*8192, cat + 256, stats);
        }
    }
    fin_kernel<<<1, 256, 0, stream>>>(stats, 256, cntE, mean, invstd);
    apply_kernel<256><<<PTS*256/256, 256, 0, stream>>>(cat + 256, mean, invstd, g4, b4);

    // ---- Layer 5: bf16 MFMA GEMM with fused max/stats ----
    tob16_kernel<<<PTS*512/4/256, 256, 0, stream>>>(cat, catB, PTS*512/4);
    tob16_kernel<<<1024*512/4/256, 256, 0, stream>>>(W5, W5b, 1024*512/4);
    l5m_kernel<<<dim3(256, 8), 256, 0, stream>>>(catB, W5b, pmax, psum, psq);
    fin5_kernel<<<4, 256, 0, stream>>>(pmax, psum, psq, g5, b5, out);
}

// Round 5
// 1229.390 us; speedup vs baseline: 2.5480x; 1.0827x over previous
//
#include <hip/hip_runtime.h>
#include <math.h>

#define BB 32
#define NN 1024
#define KNNK 20
#define PTS (BB*NN)   // 32768

typedef __attribute__((ext_vector_type(8)))  short short8;
typedef __attribute__((ext_vector_type(4)))  float f32x4;
typedef __attribute__((ext_vector_type(16))) float f32x16;

__device__ __forceinline__ float lrelu(float v){ return v >= 0.f ? v : 0.2f*v; }

__device__ __forceinline__ unsigned short f2b(float x){
    union { float f; unsigned u; } c; c.f = x;
    unsigned r = c.u + 0x7FFFu + ((c.u >> 16) & 1u);
    return (unsigned short)(r >> 16);
}

// ---------------- squared norms per point ----------------
__global__ void sq_kernel(const float* __restrict__ x, int stride, int C, float* __restrict__ xx){
    int pn = blockIdx.x*256 + threadIdx.x;
    if (pn >= PTS) return;
    const float* r = x + (size_t)pn*stride;
    float s = 0.f;
    if ((C & 3) == 0){
        for (int c = 0; c < C; c += 4){
            float4 v = *(const float4*)&r[c];
            s = fmaf(v.x, v.x, s); s = fmaf(v.y, v.y, s);
            s = fmaf(v.z, v.z, s); s = fmaf(v.w, v.w, s);
        }
    } else {
        for (int c = 0; c < C; ++c){ float v = r[c]; s = fmaf(v, v, s); }
    }
    xx[pn] = s;
}

// ---------------- FUSED knn: distance GEMM + radix-bisection top-20, no D matrix ----------------
// (unchanged this round — see round-4 notes: conflict fix 16.8M->4.2M gave 0 dur change;
// limiter is GEMM-issue + serial bisection, needs structural change, not micro-tweaks)
template<int C>
__global__ void __launch_bounds__(512, 4) knn_kernel(const float* __restrict__ x, int stride,
                                                     const float* __restrict__ xx,
                                                     int* __restrict__ idxout){
    constexpr int KC = 8;
    __shared__ __align__(16) float Bs[2][NN][4];   // 32 KB: [k-granule][col][4]
    __shared__ float xs[NN];                       // 4 KB
    int bid = (int)blockIdx.x;
    bid = (bid & 7)*128 + (bid >> 3);
    const int b  = bid >> 5;
    const int rb = bid & 31;
    const int r0 = rb * 32;
    const int tid = threadIdx.x;
    const int wv = tid >> 6, lane = tid & 63;
    const float* xb = x + (size_t)b*NN*stride;

    if (tid < 256) *(float4*)&xs[tid*4] = *(const float4*)&xx[b*NN + tid*4];

    float acc[4][16];
    #pragma unroll
    for (int r=0;r<4;++r)
        #pragma unroll
        for (int q=0;q<16;++q) acc[r][q] = 0.f;

    const int wrow = wv*4;

    #pragma unroll 1
    for (int kc = 0; kc < C; kc += KC){
        __syncthreads();
        #pragma unroll
        for (int ps = 0; ps < 4; ++ps){
            int i = tid + ps*512;
            int col = i >> 1, half = i & 1;
            float4 v;
            if constexpr (C == 3){
                float vv[4];
                #pragma unroll
                for (int j = 0; j < 4; ++j){
                    int k = half*4 + j;
                    vv[j] = (k < 3) ? xb[(size_t)col*3 + k] : 0.f;
                }
                v = make_float4(vv[0], vv[1], vv[2], vv[3]);
            } else {
                v = *(const float4*)&xb[(size_t)col*stride + kc + half*4];
            }
            *(float4*)&Bs[half][col][0] = v;
        }
        __syncthreads();
        #pragma unroll
        for (int s = 0; s < 2; ++s){
            float4 ar[4];
            #pragma unroll
            for (int r=0;r<4;++r)
                ar[r] = *(const float4*)&Bs[s][r0 + wrow + r][0];
            #pragma unroll
            for (int q=0;q<16;++q){
                float4 bv = *(const float4*)&Bs[s][lane + 64*q][0];
                #pragma unroll
                for (int r=0;r<4;++r){
                    acc[r][q] = fmaf(ar[r].x, bv.x, acc[r][q]);
                    acc[r][q] = fmaf(ar[r].y, bv.y, acc[r][q]);
                    acc[r][q] = fmaf(ar[r].z, bv.z, acc[r][q]);
                    acc[r][q] = fmaf(ar[r].w, bv.w, acc[r][q]);
                }
            }
        }
    }

    const unsigned long long lt = (lane == 0) ? 0ull : ((~0ull) >> (64 - lane));
    #pragma unroll
    for (int r = 0; r < 4; ++r){
        const int lrow = r0 + wrow + r;
        const float xi = xs[lrow];
        unsigned u[16];
        #pragma unroll
        for (int q = 0; q < 16; ++q){
            float d = 2.f*acc[r][q] - xi - xs[lane + 64*q];
            unsigned bits = __float_as_uint(d);
            unsigned m = (bits & 0x80000000u) ? 0xFFFFFFFFu : 0x80000000u;
            u[q] = bits ^ m;
        }
        unsigned t = 0u;
        for (int bb = 31; bb >= 0; --bb){
            unsigned cand = t | (1u << bb);
            int cnt = 0;
            #pragma unroll
            for (int q = 0; q < 16; ++q)
                cnt += (int)__popcll(__ballot(u[q] >= cand));
            if (cnt >= KNNK) t = cand;
        }
        int* orow = idxout + ((size_t)b*NN + lrow) * KNNK;
        int cbase = 0;
        #pragma unroll
        for (int q = 0; q < 16; ++q){
            bool gt2 = (u[q] > t);
            unsigned long long mask = __ballot(gt2);
            if (gt2) orow[cbase + (int)__popcll(mask & lt)] = q*64 + lane;
            cbase += (int)__popcll(mask);
        }
        #pragma unroll
        for (int q = 0; q < 16; ++q){
            bool eq = (u[q] == t);
            unsigned long long mask = __ballot(eq);
            int pos = cbase + (int)__popcll(mask & lt);
            if (eq && pos < KNNK) orow[pos] = q*64 + lane;
            cbase += (int)__popcll(mask);
        }
    }
}

// ---------------- G GEMMs: G1 = X @ W[:, :C]^T ; Gd = X @ (W[:,C:]-W[:, :C])^T ----------------
template<int C, int O>
__global__ void __launch_bounds__(256) gemmG_kernel(const float* __restrict__ x, int stride,
                                                    const float* __restrict__ W,
                                                    float* __restrict__ G1, float* __restrict__ Gd){
    constexpr int KC = (C < 32 ? C : 32);
    __shared__ float Xl [KC][68];
    __shared__ float W1l[KC][68];
    __shared__ float W2l[KC][68];
    const int tid = threadIdx.x;
    const int r0 = blockIdx.x * 64;
    const int o0 = blockIdx.y * 64;
    const int rt = tid & 15, ct = tid >> 4;

    float a1[4][4] = {{0.f}}, a2[4][4] = {{0.f}};
    for (int kc = 0; kc < C; kc += KC){
        __syncthreads();
        for (int i = tid; i < KC*64; i += 256){
            int k = i % KC, rr = i / KC;
            Xl [k][rr] = x[(size_t)(r0+rr)*stride + kc + k];
            W1l[k][rr] = W[(size_t)(o0+rr)*(2*C) + kc + k];
            W2l[k][rr] = W[(size_t)(o0+rr)*(2*C) + C + kc + k];
        }
        __syncthreads();
        #pragma unroll
        for (int k = 0; k < KC; ++k){
            float4 xa = *(const float4*)&Xl [k][rt*4];
            float4 w1 = *(const float4*)&W1l[k][ct*4];
            float4 w2 = *(const float4*)&W2l[k][ct*4];
            float xv[4] = {xa.x, xa.y, xa.z, xa.w};
            #pragma unroll
            for (int i = 0; i < 4; ++i){
                a1[i][0] = fmaf(xv[i], w1.x, a1[i][0]);
                a1[i][1] = fmaf(xv[i], w1.y, a1[i][1]);
                a1[i][2] = fmaf(xv[i], w1.z, a1[i][2]);
                a1[i][3] = fmaf(xv[i], w1.w, a1[i][3]);
                a2[i][0] = fmaf(xv[i], w2.x, a2[i][0]);
                a2[i][1] = fmaf(xv[i], w2.y, a2[i][1]);
                a2[i][2] = fmaf(xv[i], w2.z, a2[i][2]);
                a2[i][3] = fmaf(xv[i], w2.w, a2[i][3]);
            }
        }
    }
    #pragma unroll
    for (int i = 0; i < 4; ++i){
        size_t row = (size_t)(r0 + rt*4 + i);
        float4 g1v = make_float4(a1[i][0], a1[i][1], a1[i][2], a1[i][3]);
        float4 gdv = make_float4(a2[i][0]-a1[i][0], a2[i][1]-a1[i][1],
                                 a2[i][2]-a1[i][2], a2[i][3]-a1[i][3]);
        *(float4*)&G1[row*O + o0 + ct*4] = g1v;
        *(float4*)&Gd[row*O + o0 + ct*4] = gdv;
    }
}

// ---------------- gather v2: LDS-staged per-(batch, 32-col chunk) ----------------
// Round-1..4 counters: gather fetched 225MB/dispatch (= zero L2 reuse of G1 rows; ideal
// unique ~17MB); XCD swizzle changed nothing -> stop relying on XCD mapping, make
// locality explicit. Block = (batch bl, col-chunk cc): stage G1[bl][:, cc:cc+32] in LDS
// (1024 x 32 f32, row stride 36 floats = 16B-aligned, 144KB; m201/AITER precedent for
// >64KB static LDS on gfx950). All 20*1024 gather reads hit LDS; G1/Gd/idx read ONCE.
// 8 threads/point x 4 cols; 64 points/pass; 16 passes. Stats: wave shuffle-reduce then
// atomics (order change = fp32 noise ~1e-5 on 655K-element means; atomics were already
// order-nondeterministic).
template<int O>
__global__ void __launch_bounds__(512) gatherB_kernel(const float* __restrict__ G1,
                                                      const float* __restrict__ Gd,
                                                      const int* __restrict__ idxg, int bgbase,
                                                      float* __restrict__ catslice,
                                                      float* __restrict__ stats){
    __shared__ __align__(16) float G1s[1024][36];   // 144KB
    __shared__ int nbs[64][KNNK];                   // 5.1KB
    const int bl = blockIdx.x;          // batch index within this G1 chunk
    const int cc = blockIdx.y * 32;     // col-chunk base
    const int tid = threadIdx.x;
    const size_t prow = (size_t)bl*1024;

    // stage G1 cols [cc, cc+32) of all 1024 rows (coalesced float4)
    for (int i = tid; i < 8192; i += 512){
        int row = i >> 3, q8 = i & 7;
        float4 v = *(const float4*)&G1[(prow + row)*O + cc + q8*4];
        *(float4*)&G1s[row][q8*4] = v;
    }

    const int c4 = (tid & 7)*4;
    const int pq = tid >> 3;            // point-within-pass 0..63
    const int lane = tid & 63;
    float S1[4] = {0.f,0.f,0.f,0.f}, S2[4] = {0.f,0.f,0.f,0.f};

    for (int ps = 0; ps < 16; ++ps){
        __syncthreads();                 // guards G1 staging (ps=0) + nbs reuse
        for (int i = tid; i < 64*KNNK; i += 512){
            int pp = i / KNNK, kk = i - (i/KNNK)*KNNK;
            nbs[pp][kk] = idxg[((size_t)bgbase + prow + ps*64 + pp)*KNNK + kk];
        }
        __syncthreads();
        const int p = ps*64 + pq;
        float4 dv = *(const float4*)&Gd[(prow + p)*O + cc + c4];
        float d[4] = {dv.x, dv.y, dv.z, dv.w};
        float mx[4] = {-INFINITY,-INFINITY,-INFINITY,-INFINITY};
        float ls[4] = {0.f,0.f,0.f,0.f}, lq[4] = {0.f,0.f,0.f,0.f};
        #pragma unroll
        for (int kk = 0; kk < KNNK; ++kk){
            int row = nbs[pq][kk];
            float4 gv = *(const float4*)&G1s[row][c4];
            float ga[4] = {gv.x, gv.y, gv.z, gv.w};
            #pragma unroll
            for (int c = 0; c < 4; ++c){
                mx[c] = fmaxf(mx[c], ga[c]);
                ls[c] += ga[c];
                lq[c] = fmaf(ga[c], ga[c], lq[c]);
            }
        }
        float4 outv;
        float* op = &outv.x;
        #pragma unroll
        for (int c = 0; c < 4; ++c){
            S1[c] += ls[c] + 20.f*d[c];
            S2[c] += lq[c] + 2.f*d[c]*ls[c] + 20.f*d[c]*d[c];
            op[c] = mx[c] + d[c];
        }
        *(float4*)&catslice[((size_t)bgbase + prow + p)*512 + cc + c4] = outv;
    }

    // reduce across the 8 point-groups within each wave (lanes sharing lane&7 = same cols)
    #pragma unroll
    for (int c = 0; c < 4; ++c){
        #pragma unroll
        for (int m = 8; m < 64; m <<= 1){
            S1[c] += __shfl_xor(S1[c], m);
            S2[c] += __shfl_xor(S2[c], m);
        }
    }
    if (lane < 8){
        int rep = ((int)blockIdx.x*8 + (int)blockIdx.y) & 63;
        #pragma unroll
        for (int c = 0; c < 4; ++c){
            atomicAdd(&stats[rep*2*O + cc + lane*4 + c],     S1[c]);
            atomicAdd(&stats[rep*2*O + O + cc + lane*4 + c], S2[c]);
        }
    }
}

// ---------------- finalize BN stats ----------------
__global__ void fin_kernel(const float* __restrict__ stats, int O, float cnt,
                           float* __restrict__ mean, float* __restrict__ invstd){
    int o = threadIdx.x;
    if (o >= O) return;
    float s1 = 0.f, s2 = 0.f;
    for (int r = 0; r < 64; ++r){
        s1 += stats[r*2*O + o];
        s2 += stats[r*2*O + O + o];
    }
    float m = s1 / cnt;
    float v = s2 / cnt - m*m;
    mean[o] = m;
    invstd[o] = rsqrtf(v + 1e-5f);
}

// ---------------- apply BN+LReLU in place on cat slice ----------------
template<int O>
__global__ void apply_kernel(float* __restrict__ catslice,
                             const float* __restrict__ mean, const float* __restrict__ invstd,
                             const float* __restrict__ g, const float* __restrict__ bt){
    int i = blockIdx.x*256 + threadIdx.x;
    int pn = i / O, o = i - pn*O;
    float* p = &catslice[(size_t)pn*512 + o];
    float hn = (*p - mean[o]) * invstd[o] * g[o] + bt[o];
    *p = lrelu(hn);
}

// ---------------- fp32 -> bf16 conversion (4 elems/thread) ----------------
__global__ void tob16_kernel(const float* __restrict__ src, unsigned short* __restrict__ dst, int n4){
    int i = blockIdx.x*256 + threadIdx.x;
    if (i >= n4) return;
    float4 v = *(const float4*)&src[(size_t)i*4];
    ushort4 o;
    o.x = f2b(v.x); o.y = f2b(v.y); o.z = f2b(v.z); o.w = f2b(v.w);
    *(ushort4*)&dst[(size_t)i*4] = o;
}

// ---------------- layer 5 MFMA: 32x32x16 frags, 64x64/wave, 128x128/block ----------------
__global__ void __launch_bounds__(256) l5m_kernel(const unsigned short* __restrict__ Am,
                                                  const unsigned short* __restrict__ Bm,
                                                  float* __restrict__ pmax,
                                                  float* __restrict__ psum,
                                                  float* __restrict__ psq){
    __shared__ __align__(16) unsigned short As[128][64];
    __shared__ __align__(16) unsigned short Bs[128][64];
    const int tid = threadIdx.x;
    const int r0 = blockIdx.x * 128;
    const int o0 = blockIdx.y * 128;
    const int w = tid >> 6, lane = tid & 63;
    const int m32 = lane & 31, kh = lane >> 5;
    const int wm = (w & 1) * 64;
    const int wn = (w >> 1) * 64;

    f32x16 acc[2][2];
    #pragma unroll
    for (int i=0;i<2;++i)
        #pragma unroll
        for (int j=0;j<2;++j)
            #pragma unroll
            for (int r=0;r<16;++r) acc[i][j][r] = 0.f;

    for (int kc = 0; kc < 512; kc += 64){
        __syncthreads();
        #pragma unroll
        for (int t = 0; t < 4; ++t){
            int i = tid + t*256;
            int rr = i >> 3, ch = i & 7;
            int sl = ch ^ (rr & 7);
            *(uint4*)&As[rr][sl*8] = *(const uint4*)&Am[(size_t)(r0+rr)*512 + kc + ch*8];
            *(uint4*)&Bs[rr][sl*8] = *(const uint4*)&Bm[(size_t)(o0+rr)*512 + kc + ch*8];
        }
        __syncthreads();
        #pragma unroll
        for (int q = 0; q < 4; ++q){
            int lk = q*2 + kh;
            short8 a[2], bfr[2];
            #pragma unroll
            for (int mb = 0; mb < 2; ++mb){
                int rA = wm + mb*32 + m32;
                a[mb] = *(const short8*)&As[rA][(lk ^ (rA & 7))*8];
            }
            #pragma unroll
            for (int nb = 0; nb < 2; ++nb){
                int rB = wn + nb*32 + m32;
                bfr[nb] = *(const short8*)&Bs[rB][(lk ^ (rB & 7))*8];
            }
            #pragma unroll
            for (int mb = 0; mb < 2; ++mb)
                #pragma unroll
                for (int nb = 0; nb < 2; ++nb)
                    acc[mb][nb] = __builtin_amdgcn_mfma_f32_32x32x16_bf16(a[mb], bfr[nb], acc[mb][nb], 0, 0, 0);
        }
    }
    __syncthreads();
    float* red = (float*)&As[0][0];
    #pragma unroll
    for (int nb = 0; nb < 2; ++nb){
        float mx = -INFINITY, s1 = 0.f, s2 = 0.f;
        #pragma unroll
        for (int mb = 0; mb < 2; ++mb)
            #pragma unroll
            for (int r = 0; r < 16; ++r){
                float v = acc[mb][nb][r];
                mx = fmaxf(mx, v); s1 += v; s2 = fmaf(v, v, s2);
            }
        mx = fmaxf(mx, __shfl_xor(mx, 32));
        s1 += __shfl_xor(s1, 32);
        s2 += __shfl_xor(s2, 32);
        if (lane < 32){
            int col = wn + nb*32 + m32;
            float* p = red + ((size_t)(w & 1) * 128 + col) * 3;
            p[0] = mx; p[1] = s1; p[2] = s2;
        }
    }
    __syncthreads();
    if (tid < 128){
        const float* p0 = red + (size_t)tid*3;
        const float* p1 = red + (size_t)(128 + tid)*3;
        float mx = fmaxf(p0[0], p1[0]);
        float s1 = p0[1] + p1[1];
        float s2 = p0[2] + p1[2];
        size_t pi = (size_t)blockIdx.x*1024 + o0 + tid;
        pmax[pi] = mx; psum[pi] = s1; psq[pi] = s2;
    }
}

__global__ void fin5_kernel(const float* __restrict__ pmax, const float* __restrict__ psum,
                            const float* __restrict__ psq,
                            const float* __restrict__ g, const float* __restrict__ bt,
                            float* __restrict__ out){
    int o = blockIdx.x*256 + threadIdx.x; // 1024 total
    float s1 = 0.f, s2 = 0.f;
    for (int r = 0; r < 256; ++r){
        s1 += psum[(size_t)r*1024 + o];
        s2 += psq [(size_t)r*1024 + o];
    }
    float m  = s1 / 32768.f;
    float v  = s2 / 32768.f - m*m;
    float is = rsqrtf(v + 1e-5f);
    float gg = g[o], bb2 = bt[o];
    for (int b = 0; b < 32; ++b){
        float mx = -INFINITY;
        #pragma unroll
        for (int ns = 0; ns < 8; ++ns) mx = fmaxf(mx, pmax[((size_t)b*8 + ns)*1024 + o]);
        float hn = (mx - m) * is * gg + bb2;
        out[(size_t)b*1024 + o] = lrelu(hn);
    }
}

extern "C" void kernel_launch(void* const* d_in, const int* in_sizes, int n_in,
                              void* d_out, int out_size, void* d_ws, size_t ws_size,
                              hipStream_t stream) {
    (void)in_sizes; (void)n_in; (void)out_size;
    const float* x  = (const float*)d_in[0];
    const float* W1 = (const float*)d_in[1];  const float* g1 = (const float*)d_in[2];  const float* b1 = (const float*)d_in[3];
    const float* W2 = (const float*)d_in[4];  const float* g2 = (const float*)d_in[5];  const float* b2 = (const float*)d_in[6];
    const float* W3 = (const float*)d_in[7];  const float* g3 = (const float*)d_in[8];  const float* b3 = (const float*)d_in[9];
    const float* W4 = (const float*)d_in[10]; const float* g4 = (const float*)d_in[11]; const float* b4 = (const float*)d_in[12];
    const float* W5 = (const float*)d_in[13]; const float* g5 = (const float*)d_in[14]; const float* b5 = (const float*)d_in[15];
    float* out = (float*)d_out;

    const size_t fixedBytes = (size_t)PTS*512*4 + (size_t)PTS*KNNK*4 + (size_t)PTS*4
                            + (size_t)64*2*256*4 + 2048*4 + 3*(size_t)256*1024*4
                            + (size_t)1024*512*2;
    int CB;
    if      (ws_size >= fixedBytes + (size_t)32*NN*NN*4) CB = 32;
    else if (ws_size >= fixedBytes + (size_t)16*NN*NN*4) CB = 16;
    else                                                 CB = 8;
    const size_t Rbytes = (size_t)CB*NN*NN*4;

    char* wsp = (char*)d_ws;
    float* cat    = (float*)wsp; wsp += (size_t)PTS*512*4;
    char*  R      = wsp;         wsp += Rbytes;
    int*   idx    = (int*)  wsp; wsp += (size_t)PTS*KNNK*4;
    float* xx     = (float*)wsp; wsp += (size_t)PTS*4;
    float* stats  = (float*)wsp; wsp += (size_t)64*2*256*4;
    float* mean   = (float*)wsp; wsp += 1024*4;
    float* invstd = (float*)wsp; wsp += 1024*4;
    float* pmax   = (float*)wsp; wsp += (size_t)256*1024*4;
    float* psum   = (float*)wsp; wsp += (size_t)256*1024*4;
    float* psq    = (float*)wsp; wsp += (size_t)256*1024*4;
    unsigned short* W5b = (unsigned short*)wsp; wsp += (size_t)1024*512*2;

    float* G1    = (float*)R;
    float* GdS   = (float*)(R + (size_t)16*1024*1024);
    float* GdB   = (float*)(R + (size_t)32*1024*1024);
    unsigned short* catB = (unsigned short*)R;

    const float cntE = (float)(PTS*KNNK);
    const bool bigG = (Rbytes >= (size_t)64*1024*1024);

    // ---- Layer 1: C=3 -> O=64 ----
    sq_kernel<<<PTS/256, 256, 0, stream>>>(x, 3, 3, xx);
    knn_kernel<3><<<1024, 512, 0, stream>>>(x, 3, xx, idx);
    hipMemsetAsync(stats, 0, 64*2*256*4, stream);
    gemmG_kernel<3,64><<<dim3(512,1), 256, 0, stream>>>(x, 3, W1, G1, GdS);
    gatherB_kernel<64><<<dim3(32,2), 512, 0, stream>>>(G1, GdS, idx, 0, cat + 0, stats);
    fin_kernel<<<1, 64, 0, stream>>>(stats, 64, cntE, mean, invstd);
    apply_kernel<64><<<PTS*64/256, 256, 0, stream>>>(cat + 0, mean, invstd, g1, b1);

    // ---- Layer 2: C=64 -> O=64 ----
    sq_kernel<<<PTS/256, 256, 0, stream>>>(cat + 0, 512, 64, xx);
    knn_kernel<64><<<1024, 512, 0, stream>>>(cat + 0, 512, xx, idx);
    hipMemsetAsync(stats, 0, 64*2*256*4, stream);
    gemmG_kernel<64,64><<<dim3(512,1), 256, 0, stream>>>(cat + 0, 512, W2, G1, GdS);
    gatherB_kernel<64><<<dim3(32,2), 512, 0, stream>>>(G1, GdS, idx, 0, cat + 64, stats);
    fin_kernel<<<1, 64, 0, stream>>>(stats, 64, cntE, mean, invstd);
    apply_kernel<64><<<PTS*64/256, 256, 0, stream>>>(cat + 64, mean, invstd, g2, b2);

    // ---- Layer 3: C=64 -> O=128 ----
    sq_kernel<<<PTS/256, 256, 0, stream>>>(cat + 64, 512, 64, xx);
    knn_kernel<64><<<1024, 512, 0, stream>>>(cat + 64, 512, xx, idx);
    hipMemsetAsync(stats, 0, 64*2*256*4, stream);
    gemmG_kernel<64,128><<<dim3(512,2), 256, 0, stream>>>(cat + 64, 512, W3, G1, GdS);
    gatherB_kernel<128><<<dim3(32,4), 512, 0, stream>>>(G1, GdS, idx, 0, cat + 128, stats);
    fin_kernel<<<1, 128, 0, stream>>>(stats, 128, cntE, mean, invstd);
    apply_kernel<128><<<PTS*128/256, 256, 0, stream>>>(cat + 128, mean, invstd, g3, b3);

    // ---- Layer 4: C=128 -> O=256 ----
    sq_kernel<<<PTS/256, 256, 0, stream>>>(cat + 128, 512, 128, xx);
    knn_kernel<128><<<1024, 512, 0, stream>>>(cat + 128, 512, xx, idx);
    hipMemsetAsync(stats, 0, 64*2*256*4, stream);
    if (bigG){
        gemmG_kernel<128,256><<<dim3(512,4), 256, 0, stream>>>(cat + 128, 512, W4, G1, GdB);
        gatherB_kernel<256><<<dim3(32,8), 512, 0, stream>>>(G1, GdB, idx, 0, cat + 256, stats);
    } else {
        for (int bg = 0; bg < 4; ++bg){
            gemmG_kernel<128,256><<<dim3(128,4), 256, 0, stream>>>(cat + 128 + (size_t)bg*8192*512, 512, W4, G1, GdS);
            gatherB_kernel<256><<<dim3(8,8), 512, 0, stream>>>(G1, GdS, idx, bg*8192, cat + 256, stats);
        }
    }
    fin_kernel<<<1, 256, 0, stream>>>(stats, 256, cntE, mean, invstd);
    apply_kernel<256><<<PTS*256/256, 256, 0, stream>>>(cat + 256, mean, invstd, g4, b4);

    // ---- Layer 5: bf16 MFMA GEMM with fused max/stats ----
    tob16_kernel<<<PTS*512/4/256, 256, 0, stream>>>(cat, catB, PTS*512/4);
    tob16_kernel<<<1024*512/4/256, 256, 0, stream>>>(W5, W5b, 1024*512/4);
    l5m_kernel<<<dim3(256, 8), 256, 0, stream>>>(catB, W5b, pmax, psum, psq);
    fin5_kernel<<<4, 256, 0, stream>>>(pmax, psum, psq, g5, b5, out);
}

// Round 7
// 1215.525 us; speedup vs baseline: 2.5771x; 1.0114x over previous
//
#include <hip/hip_runtime.h>
#include <math.h>

#define BB 32
#define NN 1024
#define KNNK 20
#define PTS (BB*NN)   // 32768

typedef __attribute__((ext_vector_type(8)))  short short8;
typedef __attribute__((ext_vector_type(4)))  float f32x4;
typedef __attribute__((ext_vector_type(16))) float f32x16;

__device__ __forceinline__ float lrelu(float v){ return v >= 0.f ? v : 0.2f*v; }

__device__ __forceinline__ unsigned short f2b(float x){
    union { float f; unsigned u; } c; c.f = x;
    unsigned r = c.u + 0x7FFFu + ((c.u >> 16) & 1u);
    return (unsigned short)(r >> 16);
}

// direct HBM->LDS 16B async copy: LDS dest = wave-uniform base + lane*16, global src per-lane
__device__ __forceinline__ void glds16(const float* g, float* l){
    __builtin_amdgcn_global_load_lds(
        (const __attribute__((address_space(1))) unsigned int*)g,
        (__attribute__((address_space(3))) unsigned int*)l,
        16, 0, 0);
}

// ---------------- squared norms per point ----------------
__global__ void sq_kernel(const float* __restrict__ x, int stride, int C, float* __restrict__ xx){
    int pn = blockIdx.x*256 + threadIdx.x;
    if (pn >= PTS) return;
    const float* r = x + (size_t)pn*stride;
    float s = 0.f;
    if ((C & 3) == 0){
        for (int c = 0; c < C; c += 4){
            float4 v = *(const float4*)&r[c];
            s = fmaf(v.x, v.x, s); s = fmaf(v.y, v.y, s);
            s = fmaf(v.z, v.z, s); s = fmaf(v.w, v.w, s);
        }
    } else {
        for (int c = 0; c < C; ++c){ float v = r[c]; s = fmaf(v, v, s); }
    }
    xx[pn] = s;
}

// ---------------- FUSED knn v4: global_load_lds, prefetch AFTER barrier ----------------
// v3 (round 6) RACED: prefetch for chunk c+1 was issued BEFORE __syncthreads(), so a fast
// wave overwrote buf[cur^1] while lagging waves still computed on it (absmax 2.53), and the
// barrier's vmcnt(0) drained the prefetch immediately (no hiding). v4: prefetch issued
// immediately AFTER the barrier —
//   for c: BARRIER(A) [drains chunk c loads + fences prev compute];
//          prefetch c+1 -> buf[cur^1]  [safe: (A) proves all waves done reading it];
//          compute buf[cur]            [chunk c+1 loads fly under this].
// One barrier per chunk. FMA order + epilogue unchanged -> bit-identical distances to the
// round-5 passing version.
template<int C>
__global__ void __launch_bounds__(512, 4) knn_kernel(const float* __restrict__ x, int stride,
                                                     const float* __restrict__ xx,
                                                     int* __restrict__ idxout){
    constexpr int KC = 8;
    constexpr int NCH = (C + KC - 1)/KC;
    __shared__ __align__(16) float Bs[2][2][NN][4];   // 64 KB: [buf][k-granule][col][4]
    __shared__ float xs[NN];                          // 4 KB
    int bid = (int)blockIdx.x;
    bid = (bid & 7)*128 + (bid >> 3);
    const int b  = bid >> 5;
    const int rb = bid & 31;
    const int r0 = rb * 32;
    const int tid = threadIdx.x;
    const int wv = tid >> 6, lane = tid & 63;
    const float* xb = x + (size_t)b*NN*stride;

    if (tid < 256) *(float4*)&xs[tid*4] = *(const float4*)&xx[b*NN + tid*4];

    float acc[4][16];
    #pragma unroll
    for (int r=0;r<4;++r)
        #pragma unroll
        for (int q=0;q<16;++q) acc[r][q] = 0.f;

    const int wrow = wv*4;

    if constexpr (C == 3){
        // single chunk, zero-padded reg staging (can't zero-fill via global_load_lds)
        #pragma unroll
        for (int ps = 0; ps < 4; ++ps){
            int i = tid + ps*512;
            int col = i >> 1, half = i & 1;
            float vv[4];
            #pragma unroll
            for (int j = 0; j < 4; ++j){
                int k = half*4 + j;
                vv[j] = (k < 3) ? xb[(size_t)col*3 + k] : 0.f;
            }
            *(float4*)&Bs[0][half][col][0] = make_float4(vv[0],vv[1],vv[2],vv[3]);
        }
    } else {
        // issue chunk 0 into buf 0: wave wv covers m = wv*4+j -> granule g=m>>4, cols (m&15)*64..+63
        #pragma unroll
        for (int j = 0; j < 4; ++j){
            int m = wv*4 + j;
            int g = m >> 4, c0 = (m & 15)*64;
            glds16(&xb[(size_t)(c0 + lane)*stride + g*4], &Bs[0][g][c0][0]);
        }
    }

    #pragma unroll 1
    for (int c = 0; c < NCH; ++c){
        const int cur = c & 1;
        __syncthreads();   // (A): chunk c staged (vmcnt drain) + all waves done with buf[cur^1]
        // prefetch chunk c+1 into the other buffer — flies under this chunk's compute
        if (C > 8 && c + 1 < NCH){
            const int kc1 = (c + 1)*KC;
            #pragma unroll
            for (int j = 0; j < 4; ++j){
                int m = wv*4 + j;
                int g = m >> 4, c0 = (m & 15)*64;
                glds16(&xb[(size_t)(c0 + lane)*stride + kc1 + g*4], &Bs[cur ^ 1][g][c0][0]);
            }
        }
        #pragma unroll
        for (int s = 0; s < 2; ++s){
            float4 ar[4];
            #pragma unroll
            for (int r=0;r<4;++r)
                ar[r] = *(const float4*)&Bs[cur][s][r0 + wrow + r][0];
            #pragma unroll
            for (int q=0;q<16;++q){
                float4 bv = *(const float4*)&Bs[cur][s][lane + 64*q][0];
                #pragma unroll
                for (int r=0;r<4;++r){
                    acc[r][q] = fmaf(ar[r].x, bv.x, acc[r][q]);
                    acc[r][q] = fmaf(ar[r].y, bv.y, acc[r][q]);
                    acc[r][q] = fmaf(ar[r].z, bv.z, acc[r][q]);
                    acc[r][q] = fmaf(ar[r].w, bv.w, acc[r][q]);
                }
            }
        }
    }

    const unsigned long long lt = (lane == 0) ? 0ull : ((~0ull) >> (64 - lane));
    #pragma unroll
    for (int r = 0; r < 4; ++r){
        const int lrow = r0 + wrow + r;
        const float xi = xs[lrow];
        unsigned u[16];
        #pragma unroll
        for (int q = 0; q < 16; ++q){
            float d = 2.f*acc[r][q] - xi - xs[lane + 64*q];
            unsigned bits = __float_as_uint(d);
            unsigned m = (bits & 0x80000000u) ? 0xFFFFFFFFu : 0x80000000u;
            u[q] = bits ^ m;
        }
        unsigned t = 0u;
        for (int bb = 31; bb >= 0; --bb){
            unsigned cand = t | (1u << bb);
            int cnt = 0;
            #pragma unroll
            for (int q = 0; q < 16; ++q)
                cnt += (int)__popcll(__ballot(u[q] >= cand));
            if (cnt >= KNNK) t = cand;
        }
        int* orow = idxout + ((size_t)b*NN + lrow) * KNNK;
        int cbase = 0;
        #pragma unroll
        for (int q = 0; q < 16; ++q){
            bool gt2 = (u[q] > t);
            unsigned long long mask = __ballot(gt2);
            if (gt2) orow[cbase + (int)__popcll(mask & lt)] = q*64 + lane;
            cbase += (int)__popcll(mask);
        }
        #pragma unroll
        for (int q = 0; q < 16; ++q){
            bool eq = (u[q] == t);
            unsigned long long mask = __ballot(eq);
            int pos = cbase + (int)__popcll(mask & lt);
            if (eq && pos < KNNK) orow[pos] = q*64 + lane;
            cbase += (int)__popcll(mask);
        }
    }
}

// ---------------- G GEMMs: G1 = X @ W[:, :C]^T ; Gd = X @ (W[:,C:]-W[:, :C])^T ----------------
template<int C, int O>
__global__ void __launch_bounds__(256) gemmG_kernel(const float* __restrict__ x, int stride,
                                                    const float* __restrict__ W,
                                                    float* __restrict__ G1, float* __restrict__ Gd){
    constexpr int KC = (C < 32 ? C : 32);
    __shared__ float Xl [KC][68];
    __shared__ float W1l[KC][68];
    __shared__ float W2l[KC][68];
    const int tid = threadIdx.x;
    const int r0 = blockIdx.x * 64;
    const int o0 = blockIdx.y * 64;
    const int rt = tid & 15, ct = tid >> 4;

    float a1[4][4] = {{0.f}}, a2[4][4] = {{0.f}};
    for (int kc = 0; kc < C; kc += KC){
        __syncthreads();
        for (int i = tid; i < KC*64; i += 256){
            int k = i % KC, rr = i / KC;
            Xl [k][rr] = x[(size_t)(r0+rr)*stride + kc + k];
            W1l[k][rr] = W[(size_t)(o0+rr)*(2*C) + kc + k];
            W2l[k][rr] = W[(size_t)(o0+rr)*(2*C) + C + kc + k];
        }
        __syncthreads();
        #pragma unroll
        for (int k = 0; k < KC; ++k){
            float4 xa = *(const float4*)&Xl [k][rt*4];
            float4 w1 = *(const float4*)&W1l[k][ct*4];
            float4 w2 = *(const float4*)&W2l[k][ct*4];
            float xv[4] = {xa.x, xa.y, xa.z, xa.w};
            #pragma unroll
            for (int i = 0; i < 4; ++i){
                a1[i][0] = fmaf(xv[i], w1.x, a1[i][0]);
                a1[i][1] = fmaf(xv[i], w1.y, a1[i][1]);
                a1[i][2] = fmaf(xv[i], w1.z, a1[i][2]);
                a1[i][3] = fmaf(xv[i], w1.w, a1[i][3]);
                a2[i][0] = fmaf(xv[i], w2.x, a2[i][0]);
                a2[i][1] = fmaf(xv[i], w2.y, a2[i][1]);
                a2[i][2] = fmaf(xv[i], w2.z, a2[i][2]);
                a2[i][3] = fmaf(xv[i], w2.w, a2[i][3]);
            }
        }
    }
    #pragma unroll
    for (int i = 0; i < 4; ++i){
        size_t row = (size_t)(r0 + rt*4 + i);
        float4 g1v = make_float4(a1[i][0], a1[i][1], a1[i][2], a1[i][3]);
        float4 gdv = make_float4(a2[i][0]-a1[i][0], a2[i][1]-a1[i][1],
                                 a2[i][2]-a1[i][2], a2[i][3]-a1[i][3]);
        *(float4*)&G1[row*O + o0 + ct*4] = g1v;
        *(float4*)&Gd[row*O + o0 + ct*4] = gdv;
    }
}

// ---------------- gather v2: LDS-staged per-(batch, 32-col chunk) ----------------
template<int O>
__global__ void __launch_bounds__(512) gatherB_kernel(const float* __restrict__ G1,
                                                      const float* __restrict__ Gd,
                                                      const int* __restrict__ idxg, int bgbase,
                                                      float* __restrict__ catslice,
                                                      float* __restrict__ stats){
    __shared__ __align__(16) float G1s[1024][36];   // 144KB
    __shared__ int nbs[64][KNNK];                   // 5.1KB
    const int bl = blockIdx.x;
    const int cc = blockIdx.y * 32;
    const int tid = threadIdx.x;
    const size_t prow = (size_t)bl*1024;

    for (int i = tid; i < 8192; i += 512){
        int row = i >> 3, q8 = i & 7;
        float4 v = *(const float4*)&G1[(prow + row)*O + cc + q8*4];
        *(float4*)&G1s[row][q8*4] = v;
    }

    const int c4 = (tid & 7)*4;
    const int pq = tid >> 3;
    const int lane = tid & 63;
    float S1[4] = {0.f,0.f,0.f,0.f}, S2[4] = {0.f,0.f,0.f,0.f};

    for (int ps = 0; ps < 16; ++ps){
        __syncthreads();
        for (int i = tid; i < 64*KNNK; i += 512){
            int pp = i / KNNK, kk = i - (i/KNNK)*KNNK;
            nbs[pp][kk] = idxg[((size_t)bgbase + prow + ps*64 + pp)*KNNK + kk];
        }
        __syncthreads();
        const int p = ps*64 + pq;
        float4 dv = *(const float4*)&Gd[(prow + p)*O + cc + c4];
        float d[4] = {dv.x, dv.y, dv.z, dv.w};
        float mx[4] = {-INFINITY,-INFINITY,-INFINITY,-INFINITY};
        float ls[4] = {0.f,0.f,0.f,0.f}, lq[4] = {0.f,0.f,0.f,0.f};
        #pragma unroll
        for (int kk = 0; kk < KNNK; ++kk){
            int row = nbs[pq][kk];
            float4 gv = *(const float4*)&G1s[row][c4];
            float ga[4] = {gv.x, gv.y, gv.z, gv.w};
            #pragma unroll
            for (int c = 0; c < 4; ++c){
                mx[c] = fmaxf(mx[c], ga[c]);
                ls[c] += ga[c];
                lq[c] = fmaf(ga[c], ga[c], lq[c]);
            }
        }
        float4 outv;
        float* op = &outv.x;
        #pragma unroll
        for (int c = 0; c < 4; ++c){
            S1[c] += ls[c] + 20.f*d[c];
            S2[c] += lq[c] + 2.f*d[c]*ls[c] + 20.f*d[c]*d[c];
            op[c] = mx[c] + d[c];
        }
        *(float4*)&catslice[((size_t)bgbase + prow + p)*512 + cc + c4] = outv;
    }

    #pragma unroll
    for (int c = 0; c < 4; ++c){
        #pragma unroll
        for (int m = 8; m < 64; m <<= 1){
            S1[c] += __shfl_xor(S1[c], m);
            S2[c] += __shfl_xor(S2[c], m);
        }
    }
    if (lane < 8){
        int rep = ((int)blockIdx.x*8 + (int)blockIdx.y) & 63;
        #pragma unroll
        for (int c = 0; c < 4; ++c){
            atomicAdd(&stats[rep*2*O + cc + lane*4 + c],     S1[c]);
            atomicAdd(&stats[rep*2*O + O + cc + lane*4 + c], S2[c]);
        }
    }
}

// ---------------- finalize BN stats ----------------
__global__ void fin_kernel(const float* __restrict__ stats, int O, float cnt,
                           float* __restrict__ mean, float* __restrict__ invstd){
    int o = threadIdx.x;
    if (o >= O) return;
    float s1 = 0.f, s2 = 0.f;
    for (int r = 0; r < 64; ++r){
        s1 += stats[r*2*O + o];
        s2 += stats[r*2*O + O + o];
    }
    float m = s1 / cnt;
    float v = s2 / cnt - m*m;
    mean[o] = m;
    invstd[o] = rsqrtf(v + 1e-5f);
}

// ---------------- apply BN+LReLU in place on cat slice ----------------
template<int O>
__global__ void apply_kernel(float* __restrict__ catslice,
                             const float* __restrict__ mean, const float* __restrict__ invstd,
                             const float* __restrict__ g, const float* __restrict__ bt){
    int i = blockIdx.x*256 + threadIdx.x;
    int pn = i / O, o = i - pn*O;
    float* p = &catslice[(size_t)pn*512 + o];
    float hn = (*p - mean[o]) * invstd[o] * g[o] + bt[o];
    *p = lrelu(hn);
}

// ---------------- fp32 -> bf16 conversion (4 elems/thread) ----------------
__global__ void tob16_kernel(const float* __restrict__ src, unsigned short* __restrict__ dst, int n4){
    int i = blockIdx.x*256 + threadIdx.x;
    if (i >= n4) return;
    float4 v = *(const float4*)&src[(size_t)i*4];
    ushort4 o;
    o.x = f2b(v.x); o.y = f2b(v.y); o.z = f2b(v.z); o.w = f2b(v.w);
    *(ushort4*)&dst[(size_t)i*4] = o;
}

// ---------------- layer 5 MFMA: 32x32x16 frags, 64x64/wave, 128x128/block ----------------
__global__ void __launch_bounds__(256) l5m_kernel(const unsigned short* __restrict__ Am,
                                                  const unsigned short* __restrict__ Bm,
                                                  float* __restrict__ pmax,
                                                  float* __restrict__ psum,
                                                  float* __restrict__ psq){
    __shared__ __align__(16) unsigned short As[128][64];
    __shared__ __align__(16) unsigned short Bs[128][64];
    const int tid = threadIdx.x;
    const int r0 = blockIdx.x * 128;
    const int o0 = blockIdx.y * 128;
    const int w = tid >> 6, lane = tid & 63;
    const int m32 = lane & 31, kh = lane >> 5;
    const int wm = (w & 1) * 64;
    const int wn = (w >> 1) * 64;

    f32x16 acc[2][2];
    #pragma unroll
    for (int i=0;i<2;++i)
        #pragma unroll
        for (int j=0;j<2;++j)
            #pragma unroll
            for (int r=0;r<16;++r) acc[i][j][r] = 0.f;

    for (int kc = 0; kc < 512; kc += 64){
        __syncthreads();
        #pragma unroll
        for (int t = 0; t < 4; ++t){
            int i = tid + t*256;
            int rr = i >> 3, ch = i & 7;
            int sl = ch ^ (rr & 7);
            *(uint4*)&As[rr][sl*8] = *(const uint4*)&Am[(size_t)(r0+rr)*512 + kc + ch*8];
            *(uint4*)&Bs[rr][sl*8] = *(const uint4*)&Bm[(size_t)(o0+rr)*512 + kc + ch*8];
        }
        __syncthreads();
        #pragma unroll
        for (int q = 0; q < 4; ++q){
            int lk = q*2 + kh;
            short8 a[2], bfr[2];
            #pragma unroll
            for (int mb = 0; mb < 2; ++mb){
                int rA = wm + mb*32 + m32;
                a[mb] = *(const short8*)&As[rA][(lk ^ (rA & 7))*8];
            }
            #pragma unroll
            for (int nb = 0; nb < 2; ++nb){
                int rB = wn + nb*32 + m32;
                bfr[nb] = *(const short8*)&Bs[rB][(lk ^ (rB & 7))*8];
            }
            #pragma unroll
            for (int mb = 0; mb < 2; ++mb)
                #pragma unroll
                for (int nb = 0; nb < 2; ++nb)
                    acc[mb][nb] = __builtin_amdgcn_mfma_f32_32x32x16_bf16(a[mb], bfr[nb], acc[mb][nb], 0, 0, 0);
        }
    }
    __syncthreads();
    float* red = (float*)&As[0][0];
    #pragma unroll
    for (int nb = 0; nb < 2; ++nb){
        float mx = -INFINITY, s1 = 0.f, s2 = 0.f;
        #pragma unroll
        for (int mb = 0; mb < 2; ++mb)
            #pragma unroll
            for (int r = 0; r < 16; ++r){
                float v = acc[mb][nb][r];
                mx = fmaxf(mx, v); s1 += v; s2 = fmaf(v, v, s2);
            }
        mx = fmaxf(mx, __shfl_xor(mx, 32));
        s1 += __shfl_xor(s1, 32);
        s2 += __shfl_xor(s2, 32);
        if (lane < 32){
            int col = wn + nb*32 + m32;
            float* p = red + ((size_t)(w & 1) * 128 + col) * 3;
            p[0] = mx; p[1] = s1; p[2] = s2;
        }
    }
    __syncthreads();
    if (tid < 128){
        const float* p0 = red + (size_t)tid*3;
        const float* p1 = red + (size_t)(128 + tid)*3;
        float mx = fmaxf(p0[0], p1[0]);
        float s1 = p0[1] + p1[1];
        float s2 = p0[2] + p1[2];
        size_t pi = (size_t)blockIdx.x*1024 + o0 + tid;
        pmax[pi] = mx; psum[pi] = s1; psq[pi] = s2;
    }
}

__global__ void fin5_kernel(const float* __restrict__ pmax, const float* __restrict__ psum,
                            const float* __restrict__ psq,
                            const float* __restrict__ g, const float* __restrict__ bt,
                            float* __restrict__ out){
    int o = blockIdx.x*256 + threadIdx.x; // 1024 total
    float s1 = 0.f, s2 = 0.f;
    for (int r = 0; r < 256; ++r){
        s1 += psum[(size_t)r*1024 + o];
        s2 += psq [(size_t)r*1024 + o];
    }
    float m  = s1 / 32768.f;
    float v  = s2 / 32768.f - m*m;
    float is = rsqrtf(v + 1e-5f);
    float gg = g[o], bb2 = bt[o];
    for (int b = 0; b < 32; ++b){
        float mx = -INFINITY;
        #pragma unroll
        for (int ns = 0; ns < 8; ++ns) mx = fmaxf(mx, pmax[((size_t)b*8 + ns)*1024 + o]);
        float hn = (mx - m) * is * gg + bb2;
        out[(size_t)b*1024 + o] = lrelu(hn);
    }
}

extern "C" void kernel_launch(void* const* d_in, const int* in_sizes, int n_in,
                              void* d_out, int out_size, void* d_ws, size_t ws_size,
                              hipStream_t stream) {
    (void)in_sizes; (void)n_in; (void)out_size;
    const float* x  = (const float*)d_in[0];
    const float* W1 = (const float*)d_in[1];  const float* g1 = (const float*)d_in[2];  const float* b1 = (const float*)d_in[3];
    const float* W2 = (const float*)d_in[4];  const float* g2 = (const float*)d_in[5];  const float* b2 = (const float*)d_in[6];
    const float* W3 = (const float*)d_in[7];  const float* g3 = (const float*)d_in[8];  const float* b3 = (const float*)d_in[9];
    const float* W4 = (const float*)d_in[10]; const float* g4 = (const float*)d_in[11]; const float* b4 = (const float*)d_in[12];
    const float* W5 = (const float*)d_in[13]; const float* g5 = (const float*)d_in[14]; const float* b5 = (const float*)d_in[15];
    float* out = (float*)d_out;

    const size_t fixedBytes = (size_t)PTS*512*4 + (size_t)PTS*KNNK*4 + (size_t)PTS*4
                            + (size_t)64*2*256*4 + 2048*4 + 3*(size_t)256*1024*4
                            + (size_t)1024*512*2;
    int CB;
    if      (ws_size >= fixedBytes + (size_t)32*NN*NN*4) CB = 32;
    else if (ws_size >= fixedBytes + (size_t)16*NN*NN*4) CB = 16;
    else                                                 CB = 8;
    const size_t Rbytes = (size_t)CB*NN*NN*4;

    char* wsp = (char*)d_ws;
    float* cat    = (float*)wsp; wsp += (size_t)PTS*512*4;
    char*  R      = wsp;         wsp += Rbytes;
    int*   idx    = (int*)  wsp; wsp += (size_t)PTS*KNNK*4;
    float* xx     = (float*)wsp; wsp += (size_t)PTS*4;
    float* stats  = (float*)wsp; wsp += (size_t)64*2*256*4;
    float* mean   = (float*)wsp; wsp += 1024*4;
    float* invstd = (float*)wsp; wsp += 1024*4;
    float* pmax   = (float*)wsp; wsp += (size_t)256*1024*4;
    float* psum   = (float*)wsp; wsp += (size_t)256*1024*4;
    float* psq    = (float*)wsp; wsp += (size_t)256*1024*4;
    unsigned short* W5b = (unsigned short*)wsp; wsp += (size_t)1024*512*2;

    float* G1    = (float*)R;
    float* GdS   = (float*)(R + (size_t)16*1024*1024);
    float* GdB   = (float*)(R + (size_t)32*1024*1024);
    unsigned short* catB = (unsigned short*)R;

    const float cntE = (float)(PTS*KNNK);
    const bool bigG = (Rbytes >= (size_t)64*1024*1024);

    // ---- Layer 1: C=3 -> O=64 ----
    sq_kernel<<<PTS/256, 256, 0, stream>>>(x, 3, 3, xx);
    knn_kernel<3><<<1024, 512, 0, stream>>>(x, 3, xx, idx);
    hipMemsetAsync(stats, 0, 64*2*256*4, stream);
    gemmG_kernel<3,64><<<dim3(512,1), 256, 0, stream>>>(x, 3, W1, G1, GdS);
    gatherB_kernel<64><<<dim3(32,2), 512, 0, stream>>>(G1, GdS, idx, 0, cat + 0, stats);
    fin_kernel<<<1, 64, 0, stream>>>(stats, 64, cntE, mean, invstd);
    apply_kernel<64><<<PTS*64/256, 256, 0, stream>>>(cat + 0, mean, invstd, g1, b1);

    // ---- Layer 2: C=64 -> O=64 ----
    sq_kernel<<<PTS/256, 256, 0, stream>>>(cat + 0, 512, 64, xx);
    knn_kernel<64><<<1024, 512, 0, stream>>>(cat + 0, 512, xx, idx);
    hipMemsetAsync(stats, 0, 64*2*256*4, stream);
    gemmG_kernel<64,64><<<dim3(512,1), 256, 0, stream>>>(cat + 0, 512, W2, G1, GdS);
    gatherB_kernel<64><<<dim3(32,2), 512, 0, stream>>>(G1, GdS, idx, 0, cat + 64, stats);
    fin_kernel<<<1, 64, 0, stream>>>(stats, 64, cntE, mean, invstd);
    apply_kernel<64><<<PTS*64/256, 256, 0, stream>>>(cat + 64, mean, invstd, g2, b2);

    // ---- Layer 3: C=64 -> O=128 ----
    sq_kernel<<<PTS/256, 256, 0, stream>>>(cat + 64, 512, 64, xx);
    knn_kernel<64><<<1024, 512, 0, stream>>>(cat + 64, 512, xx, idx);
    hipMemsetAsync(stats, 0, 64*2*256*4, stream);
    gemmG_kernel<64,128><<<dim3(512,2), 256, 0, stream>>>(cat + 64, 512, W3, G1, GdS);
    gatherB_kernel<128><<<dim3(32,4), 512, 0, stream>>>(G1, GdS, idx, 0, cat + 128, stats);
    fin_kernel<<<1, 128, 0, stream>>>(stats, 128, cntE, mean, invstd);
    apply_kernel<128><<<PTS*128/256, 256, 0, stream>>>(cat + 128, mean, invstd, g3, b3);

    // ---- Layer 4: C=128 -> O=256 ----
    sq_kernel<<<PTS/256, 256, 0, stream>>>(cat + 128, 512, 128, xx);
    knn_kernel<128><<<1024, 512, 0, stream>>>(cat + 128, 512, xx, idx);
    hipMemsetAsync(stats, 0, 64*2*256*4, stream);
    if (bigG){
        gemmG_kernel<128,256><<<dim3(512,4), 256, 0, stream>>>(cat + 128, 512, W4, G1, GdB);
        gatherB_kernel<256><<<dim3(32,8), 512, 0, stream>>>(G1, GdB, idx, 0, cat + 256, stats);
    } else {
        for (int bg = 0; bg < 4; ++bg){
            gemmG_kernel<128,256><<<dim3(128,4), 256, 0, stream>>>(cat + 128 + (size_t)bg*8192*512, 512, W4, G1, GdS);
            gatherB_kernel<256><<<dim3(8,8), 512, 0, stream>>>(G1, GdS, idx, bg*8192, cat + 256, stats);
        }
    }
    fin_kernel<<<1, 256, 0, stream>>>(stats, 256, cntE, mean, invstd);
    apply_kernel<256><<<PTS*256/256, 256, 0, stream>>>(cat + 256, mean, invstd, g4, b4);

    // ---- Layer 5: bf16 MFMA GEMM with fused max/stats ----
    tob16_kernel<<<PTS*512/4/256, 256, 0, stream>>>(cat, catB, PTS*512/4);
    tob16_kernel<<<1024*512/4/256, 256, 0, stream>>>(W5, W5b, 1024*512/4);
    l5m_kernel<<<dim3(256, 8), 256, 0, stream>>>(catB, W5b, pmax, psum, psq);
    fin5_kernel<<<4, 256, 0, stream>>>(pmax, psum, psq, g5, b5, out);
}

// Round 8
// 1206.197 us; speedup vs baseline: 2.5970x; 1.0077x over previous
//
#include <hip/hip_runtime.h>
#include <math.h>

#define BB 32
#define NN 1024
#define KNNK 20
#define PTS (BB*NN)   // 32768

typedef __attribute__((ext_vector_type(8)))  short short8;
typedef __attribute__((ext_vector_type(4)))  float f32x4;
typedef __attribute__((ext_vector_type(16))) float f32x16;

__device__ __forceinline__ float lrelu(float v){ return v >= 0.f ? v : 0.2f*v; }

__device__ __forceinline__ unsigned short f2b(float x){
    union { float f; unsigned u; } c; c.f = x;
    unsigned r = c.u + 0x7FFFu + ((c.u >> 16) & 1u);
    return (unsigned short)(r >> 16);
}

// direct HBM->LDS 16B async copy: LDS dest = wave-uniform base + lane*16, global src per-lane
__device__ __forceinline__ void glds16(const float* g, float* l){
    __builtin_amdgcn_global_load_lds(
        (const __attribute__((address_space(1))) unsigned int*)g,
        (__attribute__((address_space(3))) unsigned int*)l,
        16, 0, 0);
}

// ---------------- squared norms per point ----------------
__global__ void sq_kernel(const float* __restrict__ x, int stride, int C, float* __restrict__ xx){
    int pn = blockIdx.x*256 + threadIdx.x;
    if (pn >= PTS) return;
    const float* r = x + (size_t)pn*stride;
    float s = 0.f;
    if ((C & 3) == 0){
        for (int c = 0; c < C; c += 4){
            float4 v = *(const float4*)&r[c];
            s = fmaf(v.x, v.x, s); s = fmaf(v.y, v.y, s);
            s = fmaf(v.z, v.z, s); s = fmaf(v.w, v.w, s);
        }
    } else {
        for (int c = 0; c < C; ++c){ float v = r[c]; s = fmaf(v, v, s); }
    }
    xx[pn] = s;
}

// ---------------- FUSED knn v5: batched LDS loads (anti register-starvation) ----------------
// Round-7 diagnosis: VGPR_Count=60 -> compiler kept only ~2-3 bv float4s in flight, so the
// 16 bv ds_reads per sub-chunk were consumed in tiny batches with an exposed ~120cy
// lgkmcnt wait each (~6-8 latency windows per 512-cycle FMA sub-chunk). Explains 245us vs
// 27us FMA floor, VALUBusy 55%, and why conflict/staging/occupancy fixes all nulled.
// v5: materialize ALL 4 ar + 16 bv reads into named register arrays (static indexing,
// rule #20), then sched_barrier(0) pins loads-before-FMAs (rule #18 pattern), then the
// 256 FMAs. One latency window per sub-chunk. FMA order per accumulator unchanged ->
// bit-identical distances. Staging/dbuf/epilogue identical to round-7 passing version.
template<int C>
__global__ void __launch_bounds__(512, 4) knn_kernel(const float* __restrict__ x, int stride,
                                                     const float* __restrict__ xx,
                                                     int* __restrict__ idxout){
    constexpr int KC = 8;
    constexpr int NCH = (C + KC - 1)/KC;
    __shared__ __align__(16) float Bs[2][2][NN][4];   // 64 KB: [buf][k-granule][col][4]
    __shared__ float xs[NN];                          // 4 KB
    int bid = (int)blockIdx.x;
    bid = (bid & 7)*128 + (bid >> 3);
    const int b  = bid >> 5;
    const int rb = bid & 31;
    const int r0 = rb * 32;
    const int tid = threadIdx.x;
    const int wv = tid >> 6, lane = tid & 63;
    const float* xb = x + (size_t)b*NN*stride;

    if (tid < 256) *(float4*)&xs[tid*4] = *(const float4*)&xx[b*NN + tid*4];

    float acc[4][16];
    #pragma unroll
    for (int r=0;r<4;++r)
        #pragma unroll
        for (int q=0;q<16;++q) acc[r][q] = 0.f;

    const int wrow = wv*4;

    if constexpr (C == 3){
        // single chunk, zero-padded reg staging (can't zero-fill via global_load_lds)
        #pragma unroll
        for (int ps = 0; ps < 4; ++ps){
            int i = tid + ps*512;
            int col = i >> 1, half = i & 1;
            float vv[4];
            #pragma unroll
            for (int j = 0; j < 4; ++j){
                int k = half*4 + j;
                vv[j] = (k < 3) ? xb[(size_t)col*3 + k] : 0.f;
            }
            *(float4*)&Bs[0][half][col][0] = make_float4(vv[0],vv[1],vv[2],vv[3]);
        }
    } else {
        // issue chunk 0 into buf 0: wave wv covers m = wv*4+j -> granule g=m>>4, cols (m&15)*64..+63
        #pragma unroll
        for (int j = 0; j < 4; ++j){
            int m = wv*4 + j;
            int g = m >> 4, c0 = (m & 15)*64;
            glds16(&xb[(size_t)(c0 + lane)*stride + g*4], &Bs[0][g][c0][0]);
        }
    }

    #pragma unroll 1
    for (int c = 0; c < NCH; ++c){
        const int cur = c & 1;
        __syncthreads();   // (A): chunk c staged (vmcnt drain) + all waves done with buf[cur^1]
        // prefetch chunk c+1 into the other buffer — flies under this chunk's compute
        if (C > 8 && c + 1 < NCH){
            const int kc1 = (c + 1)*KC;
            #pragma unroll
            for (int j = 0; j < 4; ++j){
                int m = wv*4 + j;
                int g = m >> 4, c0 = (m & 15)*64;
                glds16(&xb[(size_t)(c0 + lane)*stride + kc1 + g*4], &Bs[cur ^ 1][g][c0][0]);
            }
        }
        #pragma unroll
        for (int s = 0; s < 2; ++s){
            float4 ar[4];
            float4 bv[16];
            #pragma unroll
            for (int r=0;r<4;++r)
                ar[r] = *(const float4*)&Bs[cur][s][r0 + wrow + r][0];   // broadcast
            #pragma unroll
            for (int q=0;q<16;++q)
                bv[q] = *(const float4*)&Bs[cur][s][lane + 64*q][0];     // contiguous
            __builtin_amdgcn_sched_barrier(0);   // pin: all 20 loads issued before FMAs
            #pragma unroll
            for (int q=0;q<16;++q){
                #pragma unroll
                for (int r=0;r<4;++r){
                    acc[r][q] = fmaf(ar[r].x, bv[q].x, acc[r][q]);
                    acc[r][q] = fmaf(ar[r].y, bv[q].y, acc[r][q]);
                    acc[r][q] = fmaf(ar[r].z, bv[q].z, acc[r][q]);
                    acc[r][q] = fmaf(ar[r].w, bv[q].w, acc[r][q]);
                }
            }
        }
    }

    const unsigned long long lt = (lane == 0) ? 0ull : ((~0ull) >> (64 - lane));
    #pragma unroll
    for (int r = 0; r < 4; ++r){
        const int lrow = r0 + wrow + r;
        const float xi = xs[lrow];
        unsigned u[16];
        #pragma unroll
        for (int q = 0; q < 16; ++q){
            float d = 2.f*acc[r][q] - xi - xs[lane + 64*q];
            unsigned bits = __float_as_uint(d);
            unsigned m = (bits & 0x80000000u) ? 0xFFFFFFFFu : 0x80000000u;
            u[q] = bits ^ m;
        }
        unsigned t = 0u;
        for (int bb = 31; bb >= 0; --bb){
            unsigned cand = t | (1u << bb);
            int cnt = 0;
            #pragma unroll
            for (int q = 0; q < 16; ++q)
                cnt += (int)__popcll(__ballot(u[q] >= cand));
            if (cnt >= KNNK) t = cand;
        }
        int* orow = idxout + ((size_t)b*NN + lrow) * KNNK;
        int cbase = 0;
        #pragma unroll
        for (int q = 0; q < 16; ++q){
            bool gt2 = (u[q] > t);
            unsigned long long mask = __ballot(gt2);
            if (gt2) orow[cbase + (int)__popcll(mask & lt)] = q*64 + lane;
            cbase += (int)__popcll(mask);
        }
        #pragma unroll
        for (int q = 0; q < 16; ++q){
            bool eq = (u[q] == t);
            unsigned long long mask = __ballot(eq);
            int pos = cbase + (int)__popcll(mask & lt);
            if (eq && pos < KNNK) orow[pos] = q*64 + lane;
            cbase += (int)__popcll(mask);
        }
    }
}

// ---------------- G GEMMs: G1 = X @ W[:, :C]^T ; Gd = X @ (W[:,C:]-W[:, :C])^T ----------------
template<int C, int O>
__global__ void __launch_bounds__(256) gemmG_kernel(const float* __restrict__ x, int stride,
                                                    const float* __restrict__ W,
                                                    float* __restrict__ G1, float* __restrict__ Gd){
    constexpr int KC = (C < 32 ? C : 32);
    __shared__ float Xl [KC][68];
    __shared__ float W1l[KC][68];
    __shared__ float W2l[KC][68];
    const int tid = threadIdx.x;
    const int r0 = blockIdx.x * 64;
    const int o0 = blockIdx.y * 64;
    const int rt = tid & 15, ct = tid >> 4;

    float a1[4][4] = {{0.f}}, a2[4][4] = {{0.f}};
    for (int kc = 0; kc < C; kc += KC){
        __syncthreads();
        for (int i = tid; i < KC*64; i += 256){
            int k = i % KC, rr = i / KC;
            Xl [k][rr] = x[(size_t)(r0+rr)*stride + kc + k];
            W1l[k][rr] = W[(size_t)(o0+rr)*(2*C) + kc + k];
            W2l[k][rr] = W[(size_t)(o0+rr)*(2*C) + C + kc + k];
        }
        __syncthreads();
        #pragma unroll
        for (int k = 0; k < KC; ++k){
            float4 xa = *(const float4*)&Xl [k][rt*4];
            float4 w1 = *(const float4*)&W1l[k][ct*4];
            float4 w2 = *(const float4*)&W2l[k][ct*4];
            float xv[4] = {xa.x, xa.y, xa.z, xa.w};
            #pragma unroll
            for (int i = 0; i < 4; ++i){
                a1[i][0] = fmaf(xv[i], w1.x, a1[i][0]);
                a1[i][1] = fmaf(xv[i], w1.y, a1[i][1]);
                a1[i][2] = fmaf(xv[i], w1.z, a1[i][2]);
                a1[i][3] = fmaf(xv[i], w1.w, a1[i][3]);
                a2[i][0] = fmaf(xv[i], w2.x, a2[i][0]);
                a2[i][1] = fmaf(xv[i], w2.y, a2[i][1]);
                a2[i][2] = fmaf(xv[i], w2.z, a2[i][2]);
                a2[i][3] = fmaf(xv[i], w2.w, a2[i][3]);
            }
        }
    }
    #pragma unroll
    for (int i = 0; i < 4; ++i){
        size_t row = (size_t)(r0 + rt*4 + i);
        float4 g1v = make_float4(a1[i][0], a1[i][1], a1[i][2], a1[i][3]);
        float4 gdv = make_float4(a2[i][0]-a1[i][0], a2[i][1]-a1[i][1],
                                 a2[i][2]-a1[i][2], a2[i][3]-a1[i][3]);
        *(float4*)&G1[row*O + o0 + ct*4] = g1v;
        *(float4*)&Gd[row*O + o0 + ct*4] = gdv;
    }
}

// ---------------- gather v2: LDS-staged per-(batch, 32-col chunk) ----------------
template<int O>
__global__ void __launch_bounds__(512) gatherB_kernel(const float* __restrict__ G1,
                                                      const float* __restrict__ Gd,
                                                      const int* __restrict__ idxg, int bgbase,
                                                      float* __restrict__ catslice,
                                                      float* __restrict__ stats){
    __shared__ __align__(16) float G1s[1024][36];   // 144KB
    __shared__ int nbs[64][KNNK];                   // 5.1KB
    const int bl = blockIdx.x;
    const int cc = blockIdx.y * 32;
    const int tid = threadIdx.x;
    const size_t prow = (size_t)bl*1024;

    for (int i = tid; i < 8192; i += 512){
        int row = i >> 3, q8 = i & 7;
        float4 v = *(const float4*)&G1[(prow + row)*O + cc + q8*4];
        *(float4*)&G1s[row][q8*4] = v;
    }

    const int c4 = (tid & 7)*4;
    const int pq = tid >> 3;
    const int lane = tid & 63;
    float S1[4] = {0.f,0.f,0.f,0.f}, S2[4] = {0.f,0.f,0.f,0.f};

    for (int ps = 0; ps < 16; ++ps){
        __syncthreads();
        for (int i = tid; i < 64*KNNK; i += 512){
            int pp = i / KNNK, kk = i - (i/KNNK)*KNNK;
            nbs[pp][kk] = idxg[((size_t)bgbase + prow + ps*64 + pp)*KNNK + kk];
        }
        __syncthreads();
        const int p = ps*64 + pq;
        float4 dv = *(const float4*)&Gd[(prow + p)*O + cc + c4];
        float d[4] = {dv.x, dv.y, dv.z, dv.w};
        float mx[4] = {-INFINITY,-INFINITY,-INFINITY,-INFINITY};
        float ls[4] = {0.f,0.f,0.f,0.f}, lq[4] = {0.f,0.f,0.f,0.f};
        #pragma unroll
        for (int kk = 0; kk < KNNK; ++kk){
            int row = nbs[pq][kk];
            float4 gv = *(const float4*)&G1s[row][c4];
            float ga[4] = {gv.x, gv.y, gv.z, gv.w};
            #pragma unroll
            for (int c = 0; c < 4; ++c){
                mx[c] = fmaxf(mx[c], ga[c]);
                ls[c] += ga[c];
                lq[c] = fmaf(ga[c], ga[c], lq[c]);
            }
        }
        float4 outv;
        float* op = &outv.x;
        #pragma unroll
        for (int c = 0; c < 4; ++c){
            S1[c] += ls[c] + 20.f*d[c];
            S2[c] += lq[c] + 2.f*d[c]*ls[c] + 20.f*d[c]*d[c];
            op[c] = mx[c] + d[c];
        }
        *(float4*)&catslice[((size_t)bgbase + prow + p)*512 + cc + c4] = outv;
    }

    #pragma unroll
    for (int c = 0; c < 4; ++c){
        #pragma unroll
        for (int m = 8; m < 64; m <<= 1){
            S1[c] += __shfl_xor(S1[c], m);
            S2[c] += __shfl_xor(S2[c], m);
        }
    }
    if (lane < 8){
        int rep = ((int)blockIdx.x*8 + (int)blockIdx.y) & 63;
        #pragma unroll
        for (int c = 0; c < 4; ++c){
            atomicAdd(&stats[rep*2*O + cc + lane*4 + c],     S1[c]);
            atomicAdd(&stats[rep*2*O + O + cc + lane*4 + c], S2[c]);
        }
    }
}

// ---------------- finalize BN stats ----------------
__global__ void fin_kernel(const float* __restrict__ stats, int O, float cnt,
                           float* __restrict__ mean, float* __restrict__ invstd){
    int o = threadIdx.x;
    if (o >= O) return;
    float s1 = 0.f, s2 = 0.f;
    for (int r = 0; r < 64; ++r){
        s1 += stats[r*2*O + o];
        s2 += stats[r*2*O + O + o];
    }
    float m = s1 / cnt;
    float v = s2 / cnt - m*m;
    mean[o] = m;
    invstd[o] = rsqrtf(v + 1e-5f);
}

// ---------------- apply BN+LReLU in place on cat slice ----------------
template<int O>
__global__ void apply_kernel(float* __restrict__ catslice,
                             const float* __restrict__ mean, const float* __restrict__ invstd,
                             const float* __restrict__ g, const float* __restrict__ bt){
    int i = blockIdx.x*256 + threadIdx.x;
    int pn = i / O, o = i - pn*O;
    float* p = &catslice[(size_t)pn*512 + o];
    float hn = (*p - mean[o]) * invstd[o] * g[o] + bt[o];
    *p = lrelu(hn);
}

// ---------------- fp32 -> bf16 conversion (4 elems/thread) ----------------
__global__ void tob16_kernel(const float* __restrict__ src, unsigned short* __restrict__ dst, int n4){
    int i = blockIdx.x*256 + threadIdx.x;
    if (i >= n4) return;
    float4 v = *(const float4*)&src[(size_t)i*4];
    ushort4 o;
    o.x = f2b(v.x); o.y = f2b(v.y); o.z = f2b(v.z); o.w = f2b(v.w);
    *(ushort4*)&dst[(size_t)i*4] = o;
}

// ---------------- layer 5 MFMA: 32x32x16 frags, 64x64/wave, 128x128/block ----------------
__global__ void __launch_bounds__(256) l5m_kernel(const unsigned short* __restrict__ Am,
                                                  const unsigned short* __restrict__ Bm,
                                                  float* __restrict__ pmax,
                                                  float* __restrict__ psum,
                                                  float* __restrict__ psq){
    __shared__ __align__(16) unsigned short As[128][64];
    __shared__ __align__(16) unsigned short Bs[128][64];
    const int tid = threadIdx.x;
    const int r0 = blockIdx.x * 128;
    const int o0 = blockIdx.y * 128;
    const int w = tid >> 6, lane = tid & 63;
    const int m32 = lane & 31, kh = lane >> 5;
    const int wm = (w & 1) * 64;
    const int wn = (w >> 1) * 64;

    f32x16 acc[2][2];
    #pragma unroll
    for (int i=0;i<2;++i)
        #pragma unroll
        for (int j=0;j<2;++j)
            #pragma unroll
            for (int r=0;r<16;++r) acc[i][j][r] = 0.f;

    for (int kc = 0; kc < 512; kc += 64){
        __syncthreads();
        #pragma unroll
        for (int t = 0; t < 4; ++t){
            int i = tid + t*256;
            int rr = i >> 3, ch = i & 7;
            int sl = ch ^ (rr & 7);
            *(uint4*)&As[rr][sl*8] = *(const uint4*)&Am[(size_t)(r0+rr)*512 + kc + ch*8];
            *(uint4*)&Bs[rr][sl*8] = *(const uint4*)&Bm[(size_t)(o0+rr)*512 + kc + ch*8];
        }
        __syncthreads();
        #pragma unroll
        for (int q = 0; q < 4; ++q){
            int lk = q*2 + kh;
            short8 a[2], bfr[2];
            #pragma unroll
            for (int mb = 0; mb < 2; ++mb){
                int rA = wm + mb*32 + m32;
                a[mb] = *(const short8*)&As[rA][(lk ^ (rA & 7))*8];
            }
            #pragma unroll
            for (int nb = 0; nb < 2; ++nb){
                int rB = wn + nb*32 + m32;
                bfr[nb] = *(const short8*)&Bs[rB][(lk ^ (rB & 7))*8];
            }
            #pragma unroll
            for (int mb = 0; mb < 2; ++mb)
                #pragma unroll
                for (int nb = 0; nb < 2; ++nb)
                    acc[mb][nb] = __builtin_amdgcn_mfma_f32_32x32x16_bf16(a[mb], bfr[nb], acc[mb][nb], 0, 0, 0);
        }
    }
    __syncthreads();
    float* red = (float*)&As[0][0];
    #pragma unroll
    for (int nb = 0; nb < 2; ++nb){
        float mx = -INFINITY, s1 = 0.f, s2 = 0.f;
        #pragma unroll
        for (int mb = 0; mb < 2; ++mb)
            #pragma unroll
            for (int r = 0; r < 16; ++r){
                float v = acc[mb][nb][r];
                mx = fmaxf(mx, v); s1 += v; s2 = fmaf(v, v, s2);
            }
        mx = fmaxf(mx, __shfl_xor(mx, 32));
        s1 += __shfl_xor(s1, 32);
        s2 += __shfl_xor(s2, 32);
        if (lane < 32){
            int col = wn + nb*32 + m32;
            float* p = red + ((size_t)(w & 1) * 128 + col) * 3;
            p[0] = mx; p[1] = s1; p[2] = s2;
        }
    }
    __syncthreads();
    if (tid < 128){
        const float* p0 = red + (size_t)tid*3;
        const float* p1 = red + (size_t)(128 + tid)*3;
        float mx = fmaxf(p0[0], p1[0]);
        float s1 = p0[1] + p1[1];
        float s2 = p0[2] + p1[2];
        size_t pi = (size_t)blockIdx.x*1024 + o0 + tid;
        pmax[pi] = mx; psum[pi] = s1; psq[pi] = s2;
    }
}

__global__ void fin5_kernel(const float* __restrict__ pmax, const float* __restrict__ psum,
                            const float* __restrict__ psq,
                            const float* __restrict__ g, const float* __restrict__ bt,
                            float* __restrict__ out){
    int o = blockIdx.x*256 + threadIdx.x; // 1024 total
    float s1 = 0.f, s2 = 0.f;
    for (int r = 0; r < 256; ++r){
        s1 += psum[(size_t)r*1024 + o];
        s2 += psq [(size_t)r*1024 + o];
    }
    float m  = s1 / 32768.f;
    float v  = s2 / 32768.f - m*m;
    float is = rsqrtf(v + 1e-5f);
    float gg = g[o], bb2 = bt[o];
    for (int b = 0; b < 32; ++b){
        float mx = -INFINITY;
        #pragma unroll
        for (int ns = 0; ns < 8; ++ns) mx = fmaxf(mx, pmax[((size_t)b*8 + ns)*1024 + o]);
        float hn = (mx - m) * is * gg + bb2;
        out[(size_t)b*1024 + o] = lrelu(hn);
    }
}

extern "C" void kernel_launch(void* const* d_in, const int* in_sizes, int n_in,
                              void* d_out, int out_size, void* d_ws, size_t ws_size,
                              hipStream_t stream) {
    (void)in_sizes; (void)n_in; (void)out_size;
    const float* x  = (const float*)d_in[0];
    const float* W1 = (const float*)d_in[1];  const float* g1 = (const float*)d_in[2];  const float* b1 = (const float*)d_in[3];
    const float* W2 = (const float*)d_in[4];  const float* g2 = (const float*)d_in[5];  const float* b2 = (const float*)d_in[6];
    const float* W3 = (const float*)d_in[7];  const float* g3 = (const float*)d_in[8];  const float* b3 = (const float*)d_in[9];
    const float* W4 = (const float*)d_in[10]; const float* g4 = (const float*)d_in[11]; const float* b4 = (const float*)d_in[12];
    const float* W5 = (const float*)d_in[13]; const float* g5 = (const float*)d_in[14]; const float* b5 = (const float*)d_in[15];
    float* out = (float*)d_out;

    const size_t fixedBytes = (size_t)PTS*512*4 + (size_t)PTS*KNNK*4 + (size_t)PTS*4
                            + (size_t)64*2*256*4 + 2048*4 + 3*(size_t)256*1024*4
                            + (size_t)1024*512*2;
    int CB;
    if      (ws_size >= fixedBytes + (size_t)32*NN*NN*4) CB = 32;
    else if (ws_size >= fixedBytes + (size_t)16*NN*NN*4) CB = 16;
    else                                                 CB = 8;
    const size_t Rbytes = (size_t)CB*NN*NN*4;

    char* wsp = (char*)d_ws;
    float* cat    = (float*)wsp; wsp += (size_t)PTS*512*4;
    char*  R      = wsp;         wsp += Rbytes;
    int*   idx    = (int*)  wsp; wsp += (size_t)PTS*KNNK*4;
    float* xx     = (float*)wsp; wsp += (size_t)PTS*4;
    float* stats  = (float*)wsp; wsp += (size_t)64*2*256*4;
    float* mean   = (float*)wsp; wsp += 1024*4;
    float* invstd = (float*)wsp; wsp += 1024*4;
    float* pmax   = (float*)wsp; wsp += (size_t)256*1024*4;
    float* psum   = (float*)wsp; wsp += (size_t)256*1024*4;
    float* psq    = (float*)wsp; wsp += (size_t)256*1024*4;
    unsigned short* W5b = (unsigned short*)wsp; wsp += (size_t)1024*512*2;

    float* G1    = (float*)R;
    float* GdS   = (float*)(R + (size_t)16*1024*1024);
    float* GdB   = (float*)(R + (size_t)32*1024*1024);
    unsigned short* catB = (unsigned short*)R;

    const float cntE = (float)(PTS*KNNK);
    const bool bigG = (Rbytes >= (size_t)64*1024*1024);

    // ---- Layer 1: C=3 -> O=64 ----
    sq_kernel<<<PTS/256, 256, 0, stream>>>(x, 3, 3, xx);
    knn_kernel<3><<<1024, 512, 0, stream>>>(x, 3, xx, idx);
    hipMemsetAsync(stats, 0, 64*2*256*4, stream);
    gemmG_kernel<3,64><<<dim3(512,1), 256, 0, stream>>>(x, 3, W1, G1, GdS);
    gatherB_kernel<64><<<dim3(32,2), 512, 0, stream>>>(G1, GdS, idx, 0, cat + 0, stats);
    fin_kernel<<<1, 64, 0, stream>>>(stats, 64, cntE, mean, invstd);
    apply_kernel<64><<<PTS*64/256, 256, 0, stream>>>(cat + 0, mean, invstd, g1, b1);

    // ---- Layer 2: C=64 -> O=64 ----
    sq_kernel<<<PTS/256, 256, 0, stream>>>(cat + 0, 512, 64, xx);
    knn_kernel<64><<<1024, 512, 0, stream>>>(cat + 0, 512, xx, idx);
    hipMemsetAsync(stats, 0, 64*2*256*4, stream);
    gemmG_kernel<64,64><<<dim3(512,1), 256, 0, stream>>>(cat + 0, 512, W2, G1, GdS);
    gatherB_kernel<64><<<dim3(32,2), 512, 0, stream>>>(G1, GdS, idx, 0, cat + 64, stats);
    fin_kernel<<<1, 64, 0, stream>>>(stats, 64, cntE, mean, invstd);
    apply_kernel<64><<<PTS*64/256, 256, 0, stream>>>(cat + 64, mean, invstd, g2, b2);

    // ---- Layer 3: C=64 -> O=128 ----
    sq_kernel<<<PTS/256, 256, 0, stream>>>(cat + 64, 512, 64, xx);
    knn_kernel<64><<<1024, 512, 0, stream>>>(cat + 64, 512, xx, idx);
    hipMemsetAsync(stats, 0, 64*2*256*4, stream);
    gemmG_kernel<64,128><<<dim3(512,2), 256, 0, stream>>>(cat + 64, 512, W3, G1, GdS);
    gatherB_kernel<128><<<dim3(32,4), 512, 0, stream>>>(G1, GdS, idx, 0, cat + 128, stats);
    fin_kernel<<<1, 128, 0, stream>>>(stats, 128, cntE, mean, invstd);
    apply_kernel<128><<<PTS*128/256, 256, 0, stream>>>(cat + 128, mean, invstd, g3, b3);

    // ---- Layer 4: C=128 -> O=256 ----
    sq_kernel<<<PTS/256, 256, 0, stream>>>(cat + 128, 512, 128, xx);
    knn_kernel<128><<<1024, 512, 0, stream>>>(cat + 128, 512, xx, idx);
    hipMemsetAsync(stats, 0, 64*2*256*4, stream);
    if (bigG){
        gemmG_kernel<128,256><<<dim3(512,4), 256, 0, stream>>>(cat + 128, 512, W4, G1, GdB);
        gatherB_kernel<256><<<dim3(32,8), 512, 0, stream>>>(G1, GdB, idx, 0, cat + 256, stats);
    } else {
        for (int bg = 0; bg < 4; ++bg){
            gemmG_kernel<128,256><<<dim3(128,4), 256, 0, stream>>>(cat + 128 + (size_t)bg*8192*512, 512, W4, G1, GdS);
            gatherB_kernel<256><<<dim3(8,8), 512, 0, stream>>>(G1, GdS, idx, bg*8192, cat + 256, stats);
        }
    }
    fin_kernel<<<1, 256, 0, stream>>>(stats, 256, cntE, mean, invstd);
    apply_kernel<256><<<PTS*256/256, 256, 0, stream>>>(cat + 256, mean, invstd, g4, b4);

    // ---- Layer 5: bf16 MFMA GEMM with fused max/stats ----
    tob16_kernel<<<PTS*512/4/256, 256, 0, stream>>>(cat, catB, PTS*512/4);
    tob16_kernel<<<1024*512/4/256, 256, 0, stream>>>(W5, W5b, 1024*512/4);
    l5m_kernel<<<dim3(256, 8), 256, 0, stream>>>(catB, W5b, pmax, psum, psq);
    fin5_kernel<<<4, 256, 0, stream>>>(pmax, psum, psq, g5, b5, out);
}